// Round 8
// baseline (299.457 us; speedup 1.0000x reference)
//
#include <hip/hip_runtime.h>

// VectorQuantizer: z [8,64,64,64] fp32 (BCHW), embedding [8192,64] fp32.
// Outputs (concat): z_q [8,64,64,64] fp32 (BCHW), indices [32768] as fp32.
//
// R21: attack the ~110us outside k_mfma.
// R20 post-mortem: counted-vmcnt HURT k_mfma (75.4 -> 79.5) -> reverted to
// R19 __syncthreads form. Wall-time accounting: k_mfma 75 + rechk2 ~25
// (96 blocks x full 8-stage latency) + ~50us of launch overhead (7 kernels).
//  (a) k_rechk2: KSPLIT2=32 -> 256 codes/block, 2 stages; 4x concurrency,
//      1/4 latency. Overflow (pos>=CAP2) escalates directly to exact scan.
//  (b) merge2 + tier-3 + finalize fused into k_final: wave0 merges the 32
//      tier-2 partials per pixel (or marks escalate), rare escalated pixels
//      get a block-cooperative exact fp32 scan, then all threads gather z_q.
//      7 -> 5 kernel launches.
// Tiers: tier-1 fp16 MARGIN1 6e-4 -> tier-2 hi/lo 6-MFMA rescan (err ~1e-6)
// -> gap < MARGIN2 3e-5 -> exact fp32. Reference tie semantics preserved
// (ascending groups, strict >, first-min).
// Selection (R14): 6-bit candidate id in low mantissa bits (tier-1 only).
// Staging (R12): global_load_lds 16B registerless from pre-swizzled codebook.

#define NPIX 32768
#define NE   8192
#define EDIM 64
#define HW   4096
#define NSTAGE 128          // codes per LDS stage (8 subtiles of 16)
#define KSPLIT 8
#define CPS  (NE / KSPLIT)  // 1024 codes per split (tier-1)
#define NSTG (CPS / NSTAGE) // 8 stages per block (tier-1)
#define KS2  32
#define CPS2 (NE / KS2)     // 256 codes per split (tier-2)
#define NSTG2 (CPS2 / NSTAGE) // 2 stages per block (tier-2)
#define CAP2 8192           // max tier-2 items
#define MARGIN1 6.0e-4f
#define MARGIN2 3.0e-5f
#define NSET 2              // row-sets of 16 pixels per wave (PPW=32)
#define RSCL 2048.0f        // residual pre-scale (2^11)
#define RINV 4.8828125e-4f  // 2^-11

typedef _Float16 f16x8 __attribute__((ext_vector_type(8)));
typedef float f32x4  __attribute__((ext_vector_type(4)));

__device__ __forceinline__ short f2h_bits(float x) {
    _Float16 h = (_Float16)x;
    short s; __builtin_memcpy(&s, &h, 2); return s;
}
__device__ __forceinline__ float h_hi_f(float x) {
    return (float)(_Float16)x;
}
// map float to unsigned with same total order
__device__ __forceinline__ unsigned int order_u32(float f) {
    unsigned int s = __float_as_uint(f);
    return (s & 0x80000000u) ? ~s : (s | 0x80000000u);
}
// async global->LDS, 16B/lane; HW writes lane i at lds_base + i*16 (wave-uniform base)
__device__ __forceinline__ void gload_lds16(const void* g, void* l) {
    __builtin_amdgcn_global_load_lds(
        (const __attribute__((address_space(1))) void*)g,
        (__attribute__((address_space(3))) void*)l, 16, 0, 0);
}

// ---------------- prep (fused): codebook (swizzled fp16 hi + lo) + pixels ----
// esw/eswl layout = the k_mfma LDS stage image: per 64-code group, 8 combos
// (sub[4] x {k0,k1}) x 1KB; within combo, MFMA-B fragment order: slot
// frag_lane = (o&3)*16 + code_col holds 8 channels (16B). A 128-code stage =
// two consecutive 64-code groups (contiguous 16KB). eswl = scaled residuals.
__global__ __launch_bounds__(256) void k_prep(const float* __restrict__ emb,
                                              const float* __restrict__ z,
                                              float* __restrict__ e_norm,
                                              float* __restrict__ se_half,
                                              short* __restrict__ esw,
                                              short* __restrict__ eswl,
                                              float* __restrict__ zn,
                                              unsigned* __restrict__ counter) {
    if (blockIdx.x == 0 && threadIdx.x == 0) { counter[0] = 0u; }
    if (blockIdx.x < NE / 4) {
        // --- codebook: 1 code per wave, lane = channel ---
        const int wave = threadIdx.x >> 6;
        const int lane = threadIdx.x & 63;
        const int n = blockIdx.x * 4 + wave;
        float v = emb[n * EDIM + lane];
        float ss = v * v;
        #pragma unroll
        for (int off = 32; off; off >>= 1) ss += __shfl_xor(ss, off, 64);
        const float inv = 1.0f / fmaxf(sqrtf(ss), 1e-12f);
        const float en = v * inv;
        e_norm[n * EDIM + lane] = en;
        const float hf = h_hi_f(en);
        // swizzled fp16 write (c = lane)
        const int grp = n >> 6, cs = n & 63;
        const int sub = cs >> 4, colb = cs & 15;
        const int o = lane >> 3, j = lane & 7;     // o: khalf=o>>2, quad=o&3
        const int slot = ((o & 3) * 16 + colb) * 8 + j;
        const int off16 = grp * 4096 + (sub * 2 + (o >> 2)) * 512 + slot;
        esw[off16]  = f2h_bits(en);
        eswl[off16] = f2h_bits((en - hf) * RSCL);
        float s2 = en * en;
        #pragma unroll
        for (int off = 32; off; off >>= 1) s2 += __shfl_xor(s2, off, 64);
        if (lane == 0) se_half[n] = 0.5f * s2;
    } else {
        // --- pixels: single-pass normalize -> zn fp32 row-major [p][c] ---
        const int p = (blockIdx.x - NE / 4) * 256 + threadIdx.x;
        const int b = p >> 12, hw = p & (HW - 1);
        const float* zp = z + b * (EDIM * HW) + hw;
        float v[EDIM];
        #pragma unroll
        for (int c = 0; c < EDIM; ++c) v[c] = zp[c * HW];
        float ss = 0.0f;
        #pragma unroll
        for (int c = 0; c < EDIM; ++c) ss = fmaf(v[c], v[c], ss);
        const float inv = 1.0f / fmaxf(sqrtf(ss), 1e-12f);
        #pragma unroll
        for (int c4 = 0; c4 < 16; ++c4) {
            float4 o;
            o.x = v[c4 * 4 + 0] * inv;
            o.y = v[c4 * 4 + 1] * inv;
            o.z = v[c4 * 4 + 2] * inv;
            o.w = v[c4 * 4 + 3] * inv;
            *(float4*)(zn + p * EDIM + c4 * 4) = o;
        }
    }
}

// ---------------- tier-1 k_mfma: split-K partial top-2 (R19 proven) ---------
// Block: 4 waves x 32 pixels = 128 pixels, one codebook eighth (blockIdx.y).
// v = dot + 2 in [1,3]; argmin dist == argmax v (unit vectors). Low 6 mantissa
// bits carry the candidate id (stage*8+sub). Layouts (HW-verified):
// A[m=lane&15][k=quad*8+j], B[k=quad*8+j][n=lane&15], C/D row=(lane>>4)*4+reg,
// col=lane&15.
__global__ __launch_bounds__(256, 1) void k_mfma(const float* __restrict__ zn,
                                                 const short* __restrict__ esw,
                                                 float2* __restrict__ pv,   // [g][p] {b1,b2} (max-space)
                                                 unsigned* __restrict__ pi) // [g][p] i1
{
    __shared__ __align__(16) short es[2][NSTAGE * EDIM];   // 2 x 16KB

    const int tid  = threadIdx.x;             // 0..255
    const int wave = tid >> 6, lane = tid & 63;
    const int quad = lane >> 4, col = lane & 15;
    const int p0   = blockIdx.x * 128 + wave * 32;  // wave's 32 pixels (2 sets)
    const int g    = blockIdx.y;                    // codebook eighth
    const int kbase = g * CPS;

    // A fragments: 2 sets of 16 pixels; fp32 zn -> fp16 (single product)
    f16x8 ah[NSET][2];
    #pragma unroll
    for (int s = 0; s < NSET; ++s) {
        const float* zr = zn + (p0 + s * 16 + col) * EDIM;
        #pragma unroll
        for (int kc = 0; kc < 2; ++kc) {
            float f[8];
            *(float4*)(f + 0) = *(const float4*)(zr + kc * 32 + quad * 8 + 0);
            *(float4*)(f + 4) = *(const float4*)(zr + kc * 32 + quad * 8 + 4);
            #pragma unroll
            for (int i = 0; i < 8; ++i) ah[s][kc][i] = (_Float16)f[i];
        }
    }

    // top-2 state in max-space; values stuffed with 6-bit id; b1 >= b2 invariant
    float b1[NSET][4], b2[NSET][4];
    #pragma unroll
    for (int s = 0; s < NSET; ++s)
        #pragma unroll
        for (int r = 0; r < 4; ++r) { b1[s][r] = 0.0f; b2[s][r] = 0.0f; }

    const f32x4 cini = {2.0f, 2.0f, 2.0f, 2.0f};   // |z|=|e|=1 -> bias constant

    // this wave's staging window: src and dst are both uniform + lane*16
    const int combo0 = wave * 4;   // 16 combos x 1KB per 16KB stage
    const char* gsrc0 = (const char*)esw + (size_t)kbase * 128
                        + combo0 * 1024 + lane * 16;
    // prologue: issue stage 0 -> buf 0
    #pragma unroll
    for (int it = 0; it < 4; ++it)
        gload_lds16(gsrc0 + it * 1024, (char*)&es[0][0] + (combo0 + it) * 1024);

    for (int nb = 0; nb < NSTG; ++nb) {
        const int cur = nb & 1;
        __syncthreads();   // vmcnt drained: buf[cur] complete; buf[cur^1] reusable
        if (nb + 1 < NSTG) {
            const char* gsrc = gsrc0 + (size_t)(nb + 1) * (NSTAGE * EDIM * 2);
            #pragma unroll
            for (int it = 0; it < 4; ++it)
                gload_lds16(gsrc + it * 1024,
                            (char*)&es[cur ^ 1][0] + (combo0 + it) * 1024);
        }

        const short* esb = es[cur];
        #pragma unroll
        for (int sub = 0; sub < 8; ++sub) {       // 8 subtiles of 16 codes
            const short* base = esb + sub * 1024;
            const f16x8 bh0 = *(const f16x8*)(base + lane * 8);
            const f16x8 bh1 = *(const f16x8*)(base + 512 + lane * 8);
            const unsigned sid = (unsigned)((nb << 3) | sub);  // 6-bit id, uniform
            #pragma unroll
            for (int s = 0; s < NSET; ++s) {
                // 2-deep chain seeded with C = {2.0}
                f32x4 acc;
                acc = __builtin_amdgcn_mfma_f32_16x16x32_f16(ah[s][0], bh0, cini, 0, 0, 0);
                acc = __builtin_amdgcn_mfma_f32_16x16x32_f16(ah[s][1], bh1, acc, 0, 0, 0);
                #pragma unroll
                for (int r = 0; r < 4; ++r) {
                    // stuff candidate id into low mantissa bits (v_and_or_b32)
                    const float v = __uint_as_float(
                        (__float_as_uint(acc[r]) & 0xFFFFFFC0u) | sid);
                    // b1>=b2 invariant -> med3 == new 2nd-max; then running max
                    b2[s][r] = __builtin_amdgcn_fmed3f(v, b2[s][r], b1[s][r]);
                    b1[s][r] = fmaxf(b1[s][r], v);
                }
            }
        }
    }

    // recover winning index from b1's stuffed id (col is lane-implicit)
    int i1[NSET][4];
    #pragma unroll
    for (int s = 0; s < NSET; ++s)
        #pragma unroll
        for (int r = 0; r < 4; ++r) {
            const unsigned id6 = __float_as_uint(b1[s][r]) & 63u;
            i1[s][r] = kbase + (int)(id6 << 4) + col;
        }

    // merge top-2 across the 16 col-lanes (xor 1,2,4,8 stays inside quad group)
    #pragma unroll
    for (int m = 1; m <= 8; m <<= 1) {
        #pragma unroll
        for (int s = 0; s < NSET; ++s)
            #pragma unroll
            for (int r = 0; r < 4; ++r) {
                const float ob1 = __shfl_xor(b1[s][r], m, 64);
                const int   oi1 = __shfl_xor(i1[s][r], m, 64);
                const float ob2 = __shfl_xor(b2[s][r], m, 64);
                const bool take = (ob1 > b1[s][r]) || (ob1 == b1[s][r] && oi1 < i1[s][r]);
                b2[s][r] = fmaxf(fmaxf(b2[s][r], ob2), fminf(b1[s][r], ob1));
                b1[s][r] = take ? ob1 : b1[s][r];
                i1[s][r] = take ? oi1 : i1[s][r];
            }
    }
    if (col == 0) {
        #pragma unroll
        for (int s = 0; s < NSET; ++s)
            #pragma unroll
            for (int r = 0; r < 4; ++r) {
                const int p = p0 + s * 16 + quad * 4 + r;   // C/D row = quad*4 + r
                pv[g * NPIX + p] = make_float2(b1[s][r], b2[s][r]);
                pi[g * NPIX + p] = (unsigned)i1[s][r];
            }
    }
}

// ---------------- merge: combine KSPLIT partials, flag tier-2 ----------------
// Flagged pixels: idx_arr[p] = 0x80000000 | pos (tier-2 item slot). pos >= CAP2
// overflows straight to exact-scan escalation in k_final.
__global__ __launch_bounds__(256) void k_merge(const float2* __restrict__ pv,
                                               const unsigned* __restrict__ pi,
                                               unsigned* __restrict__ idx_arr,
                                               unsigned* __restrict__ list,
                                               unsigned* __restrict__ counter) {
    const int p = blockIdx.x * 256 + threadIdx.x;
    float2 v[KSPLIT]; unsigned ix[KSPLIT];
    #pragma unroll
    for (int gg = 0; gg < KSPLIT; ++gg) { v[gg] = pv[gg * NPIX + p]; ix[gg] = pi[gg * NPIX + p]; }
    // ascending group order + strict > == np first-occurrence tie semantics
    float b1 = v[0].x; unsigned i1 = ix[0]; int win = 0;
    #pragma unroll
    for (int gg = 1; gg < KSPLIT; ++gg)
        if (v[gg].x > b1) { b1 = v[gg].x; i1 = ix[gg]; win = gg; }
    float b2 = -3.0e38f;
    #pragma unroll
    for (int gg = 0; gg < KSPLIT; ++gg) {
        b2 = fmaxf(b2, v[gg].y);
        if (gg != win) b2 = fmaxf(b2, v[gg].x);
    }
    if (b1 - b2 < MARGIN1) {   // gap in v-space == gap in dist/2
        const unsigned pos = atomicAdd(&counter[0], 1u);
        if (pos < CAP2) list[pos] = p;
        idx_arr[p] = 0x80000000u | pos;
    } else {
        idx_arr[p] = i1;
    }
}

// ---------------- tier-2: hi/lo MFMA rescan of flagged pixels ---------------
// 32-way K-split (256 codes / block, 2 stages) for low per-block latency.
// Scoring: v = ah.bh + 2 + 2^-11*(al'.bh + ah.bl'), err ~1e-6.
__global__ __launch_bounds__(256, 1) void k_rechk2(const float* __restrict__ zn,
                                                   const short* __restrict__ esw,
                                                   const short* __restrict__ eswl,
                                                   const unsigned* __restrict__ list,
                                                   const unsigned* __restrict__ counter,
                                                   float2* __restrict__ pv,   // reused: [g2][item]
                                                   unsigned* __restrict__ pi) // reused: [g2][item]
{
    __shared__ __align__(16) short es[2][2][NSTAGE * EDIM];   // [buf][hi/lo] 16KB each

    int cnt = (int)counter[0]; if (cnt > CAP2) cnt = CAP2;
    const int ib = blockIdx.x * 128;          // item base for this block
    if (ib >= cnt) return;

    const int tid  = threadIdx.x;
    const int wave = tid >> 6, lane = tid & 63;
    const int quad = lane >> 4, col = lane & 15;
    const int g2   = blockIdx.y;
    const int kbase = g2 * CPS2;

    // A fragments: gathered pixel rows (clamped), fp16 hi + scaled residual lo
    f16x8 ah[NSET][2], al[NSET][2];
    #pragma unroll
    for (int s = 0; s < NSET; ++s) {
        int item = ib + wave * 32 + s * 16 + col;
        if (item > cnt - 1) item = cnt - 1;
        const float* zr = zn + (size_t)list[item] * EDIM;
        #pragma unroll
        for (int kc = 0; kc < 2; ++kc) {
            float f[8];
            *(float4*)(f + 0) = *(const float4*)(zr + kc * 32 + quad * 8 + 0);
            *(float4*)(f + 4) = *(const float4*)(zr + kc * 32 + quad * 8 + 4);
            #pragma unroll
            for (int i = 0; i < 8; ++i) {
                ah[s][kc][i] = (_Float16)f[i];
                al[s][kc][i] = (_Float16)((f[i] - h_hi_f(f[i])) * RSCL);
            }
        }
    }

    float b1[NSET][4], b2[NSET][4]; int i1[NSET][4];
    #pragma unroll
    for (int s = 0; s < NSET; ++s)
        #pragma unroll
        for (int r = 0; r < 4; ++r) { b1[s][r] = 0.0f; b2[s][r] = 0.0f; i1[s][r] = 0; }

    const f32x4 cini = {2.0f, 2.0f, 2.0f, 2.0f};
    const f32x4 zero = {0.0f, 0.0f, 0.0f, 0.0f};

    const int combo0 = wave * 4;
    const char* ghi0 = (const char*)esw  + (size_t)kbase * 128 + combo0 * 1024 + lane * 16;
    const char* glo0 = (const char*)eswl + (size_t)kbase * 128 + combo0 * 1024 + lane * 16;
    #pragma unroll
    for (int it = 0; it < 4; ++it) {
        gload_lds16(ghi0 + it * 1024, (char*)&es[0][0][0] + (combo0 + it) * 1024);
        gload_lds16(glo0 + it * 1024, (char*)&es[0][1][0] + (combo0 + it) * 1024);
    }

    for (int nb = 0; nb < NSTG2; ++nb) {
        const int cur = nb & 1;
        const int n0 = kbase + nb * NSTAGE;
        __syncthreads();
        if (nb + 1 < NSTG2) {
            const size_t soff = (size_t)(nb + 1) * (NSTAGE * EDIM * 2);
            #pragma unroll
            for (int it = 0; it < 4; ++it) {
                gload_lds16(ghi0 + soff + it * 1024,
                            (char*)&es[cur ^ 1][0][0] + (combo0 + it) * 1024);
                gload_lds16(glo0 + soff + it * 1024,
                            (char*)&es[cur ^ 1][1][0] + (combo0 + it) * 1024);
            }
        }

        const short* eh = es[cur][0];
        const short* el = es[cur][1];
        #pragma unroll
        for (int sub = 0; sub < 8; ++sub) {
            const f16x8 bh0 = *(const f16x8*)(eh + sub * 1024 + lane * 8);
            const f16x8 bh1 = *(const f16x8*)(eh + sub * 1024 + 512 + lane * 8);
            const f16x8 bl0 = *(const f16x8*)(el + sub * 1024 + lane * 8);
            const f16x8 bl1 = *(const f16x8*)(el + sub * 1024 + 512 + lane * 8);
            const int nglob = n0 + sub * 16 + col;
            #pragma unroll
            for (int s = 0; s < NSET; ++s) {
                f32x4 acc;
                acc = __builtin_amdgcn_mfma_f32_16x16x32_f16(ah[s][0], bh0, cini, 0, 0, 0);
                acc = __builtin_amdgcn_mfma_f32_16x16x32_f16(ah[s][1], bh1, acc, 0, 0, 0);
                f32x4 cor;
                cor = __builtin_amdgcn_mfma_f32_16x16x32_f16(al[s][0], bh0, zero, 0, 0, 0);
                cor = __builtin_amdgcn_mfma_f32_16x16x32_f16(ah[s][0], bl0, cor, 0, 0, 0);
                cor = __builtin_amdgcn_mfma_f32_16x16x32_f16(al[s][1], bh1, cor, 0, 0, 0);
                cor = __builtin_amdgcn_mfma_f32_16x16x32_f16(ah[s][1], bl1, cor, 0, 0, 0);
                #pragma unroll
                for (int r = 0; r < 4; ++r) {
                    const float v = fmaf(cor[r], RINV, acc[r]);
                    b2[s][r] = __builtin_amdgcn_fmed3f(v, b2[s][r], b1[s][r]);
                    const bool t = v > b1[s][r];       // strict >, n ascending
                    b1[s][r] = fmaxf(b1[s][r], v);
                    i1[s][r] = t ? nglob : i1[s][r];
                }
            }
        }
    }

    // merge top-2 across the 16 col-lanes
    #pragma unroll
    for (int m = 1; m <= 8; m <<= 1) {
        #pragma unroll
        for (int s = 0; s < NSET; ++s)
            #pragma unroll
            for (int r = 0; r < 4; ++r) {
                const float ob1 = __shfl_xor(b1[s][r], m, 64);
                const int   oi1 = __shfl_xor(i1[s][r], m, 64);
                const float ob2 = __shfl_xor(b2[s][r], m, 64);
                const bool take = (ob1 > b1[s][r]) || (ob1 == b1[s][r] && oi1 < i1[s][r]);
                b2[s][r] = fmaxf(fmaxf(b2[s][r], ob2), fminf(b1[s][r], ob1));
                b1[s][r] = take ? ob1 : b1[s][r];
                i1[s][r] = take ? oi1 : i1[s][r];
            }
    }
    if (col == 0) {
        #pragma unroll
        for (int s = 0; s < NSET; ++s)
            #pragma unroll
            for (int r = 0; r < 4; ++r) {
                const int item = ib + wave * 32 + s * 16 + quad * 4 + r;
                if (item < cnt) {
                    pv[g2 * CAP2 + item] = make_float2(b1[s][r], b2[s][r]);
                    pi[g2 * CAP2 + item] = (unsigned)i1[s][r];
                }
            }
    }
}

// ---------------- k_final: merge tier-2, rare exact scan, gather z_q ---------
// Block: 256 threads / 64 pixels. Phase A: wave0 (64 lanes = 64 pixels)
// resolves each pixel's index: non-flagged -> idx_arr; flagged -> merge the
// 32 tier-2 partials (gap >= MARGIN2) or mark escalate (also pos >= CAP2).
// Phase B: escalated pixels (rare) get a block-cooperative exact fp32 scan.
// Phase C: 4 threads/pixel gather codebook row to z_q (BCHW).
__global__ __launch_bounds__(256) void k_final(const unsigned* __restrict__ idx_arr,
                                               const float2* __restrict__ pv,
                                               const unsigned* __restrict__ pi,
                                               const float* __restrict__ e_norm,
                                               const float* __restrict__ zn,
                                               const float* __restrict__ se_half,
                                               float* __restrict__ out) {
    __shared__ int s_bidx[64];
    __shared__ int s_escp[64];
    __shared__ int s_esc;
    __shared__ unsigned long long s_key[4];

    const int tid  = threadIdx.x;
    const int wave = tid >> 6, lane = tid & 63;
    const int p0   = blockIdx.x * 64;

    if (tid == 0) s_esc = 0;
    __syncthreads();

    // ---- phase A: resolve indices (wave 0, one lane per pixel) ----
    if (wave == 0) {
        const unsigned v = idx_arr[p0 + lane];
        int bidx;
        if (!(v & 0x80000000u)) {
            bidx = (int)v;
        } else {
            const unsigned item = v & 0x7FFFFFFFu;
            if (item >= CAP2) {
                bidx = -1;                     // overflow -> exact scan
            } else {
                float b1 = -3.0e38f, b2 = -3.0e38f; unsigned i1 = 0;
                #pragma unroll
                for (int g2 = 0; g2 < KS2; ++g2) {   // ascending: first-occurrence
                    const float2 vv = pv[g2 * CAP2 + item];
                    const unsigned ii = pi[g2 * CAP2 + item];
                    if (vv.x > b1) { b2 = fmaxf(b2, b1); b1 = vv.x; i1 = ii; }
                    else           { b2 = fmaxf(b2, vv.x); }
                    b2 = fmaxf(b2, vv.y);
                }
                bidx = (b1 - b2 < MARGIN2) ? -1 : (int)i1;
            }
        }
        s_bidx[lane] = bidx;
        if (bidx < 0) {
            const int e = atomicAdd(&s_esc, 1);
            s_escp[e] = lane;
        }
    }
    __syncthreads();

    // ---- phase B: exact fp32 scan for escalated pixels (rare) ----
    const int nesc = s_esc;
    for (int e = 0; e < nesc; ++e) {
        const int p = p0 + s_escp[e];
        const int k = lane >> 4, m = lane & 15;
        const float4 zv = *(const float4*)(zn + (size_t)p * EDIM + m * 4);
        const float4* e4 = (const float4*)e_norm;
        float best = 3.0e38f; int bidx = 0;
        for (int chunk = wave; chunk < 16; chunk += 4) {   // wave's 4 chunks
            for (int t4 = 0; t4 < 32; ++t4) {              // 16 codes / iter
                float sdot[4]; int n[4];
                #pragma unroll
                for (int j = 0; j < 4; ++j) {
                    n[j] = chunk * 512 + (t4 * 4 + j) * 4 + k;
                    const float4 ev = e4[n[j] * 16 + m];
                    sdot[j] = fmaf(zv.w, ev.w, fmaf(zv.z, ev.z,
                              fmaf(zv.y, ev.y, zv.x * ev.x)));
                }
                #pragma unroll
                for (int j = 0; j < 4; ++j) sdot[j] += __shfl_xor(sdot[j], 1, 64);
                #pragma unroll
                for (int j = 0; j < 4; ++j) sdot[j] += __shfl_xor(sdot[j], 2, 64);
                #pragma unroll
                for (int j = 0; j < 4; ++j) sdot[j] += __shfl_xor(sdot[j], 4, 64);
                #pragma unroll
                for (int j = 0; j < 4; ++j) sdot[j] += __shfl_xor(sdot[j], 8, 64);
                #pragma unroll
                for (int j = 0; j < 4; ++j) {              // lane codes ascend
                    const float d = se_half[n[j]] - sdot[j];
                    if (d < best) { best = d; bidx = n[j]; }
                }
            }
        }
        #pragma unroll
        for (int mm = 1; mm <= 32; mm <<= 1) {             // wave first-min
            const float ob = __shfl_xor(best, mm, 64);
            const int   oi = __shfl_xor(bidx, mm, 64);
            if (ob < best || (ob == best && oi < bidx)) { best = ob; bidx = oi; }
        }
        if (lane == 0)
            s_key[wave] = ((unsigned long long)order_u32(best) << 32) | (unsigned)bidx;
        __syncthreads();
        if (tid == 0) {
            unsigned long long kk = s_key[0];
            #pragma unroll
            for (int w = 1; w < 4; ++w) kk = (s_key[w] < kk) ? s_key[w] : kk;
            s_bidx[s_escp[e]] = (int)(kk & 0xFFFFFFFFull);
        }
        __syncthreads();
    }

    // ---- phase C: write index + gather z_q (4 threads/pixel) ----
    const int p = p0 + lane;
    const int bidx = s_bidx[lane];
    const int q = wave;                                // channel quarter
    if (q == 0) out[NPIX * EDIM + p] = (float)bidx;
    const int b = p >> 12, hw = p & (HW - 1);
    float* op = out + b * (EDIM * HW) + hw;
    const float4* ep4 = (const float4*)(e_norm + (size_t)bidx * EDIM + q * 16);
    #pragma unroll
    for (int j = 0; j < 4; ++j) {
        const float4 ev = ep4[j];
        const int c = q * 16 + j * 4;
        op[(c + 0) * HW] = ev.x; op[(c + 1) * HW] = ev.y;   // coalesced per c
        op[(c + 2) * HW] = ev.z; op[(c + 3) * HW] = ev.w;
    }
}

extern "C" void kernel_launch(void* const* d_in, const int* in_sizes, int n_in,
                              void* d_out, int out_size, void* d_ws, size_t ws_size,
                              hipStream_t stream) {
    const float* z   = (const float*)d_in[0];
    const float* emb = (const float*)d_in[1];
    float* out = (float*)d_out;

    // workspace layout (~15.5 MB)
    float* e_norm  = (float*)d_ws;                       // 2 MB
    float* se_half = e_norm + NE * EDIM;                 // 32 KB
    short* esw  = (short*)(se_half + NE);                // 1 MB (swizzled fp16 hi)
    short* eswl = esw + NE * EDIM;                       // 1 MB (swizzled fp16 lo)
    float* zn = (float*)(eswl + NE * EDIM);              // 8 MB
    unsigned* idx_arr = (unsigned*)(zn + NPIX * EDIM);   // 128 KB
    unsigned* list    = idx_arr + NPIX;                  // 128 KB (tier-2 items)
    unsigned* counter = list + NPIX;                     // 4 B (+pad)
    float2*   pv = (float2*)(counter + 64);              // 2 MB (8xNPIX == 32xCAP2)
    unsigned* pi = (unsigned*)(pv + KSPLIT * NPIX);      // 1 MB

    k_prep<<<NE / 4 + NPIX / 256, 256, 0, stream>>>(emb, z, e_norm, se_half,
                                                    esw, eswl, zn, counter);
    k_mfma<<<dim3(NPIX / 128, KSPLIT), 256, 0, stream>>>(zn, esw, pv, pi);
    k_merge<<<NPIX / 256, 256, 0, stream>>>(pv, pi, idx_arr, list, counter);
    k_rechk2<<<dim3(CAP2 / 128, KS2), 256, 0, stream>>>(zn, esw, eswl, list,
                                                        counter, pv, pi);
    k_final<<<NPIX / 64, 256, 0, stream>>>(idx_arr, pv, pi, e_norm, zn,
                                           se_half, out);
}

// Round 9
// 248.860 us; speedup vs baseline: 1.2033x; 1.2033x over previous
//
#include <hip/hip_runtime.h>

// VectorQuantizer: z [8,64,64,64] fp32 (BCHW), embedding [8192,64] fp32.
// Outputs (concat): z_q [8,64,64,64] fp32 (BCHW), indices [32768] as fp32.
//
// R22: R19 skeleton restored + overflow-safe tiers + barrier-free k_mfma.
// R21 post-mortem: flag count at MARGIN1 is ~15-20K (not ~1.4K); CAP2
// overflow fed per-block serial exact scans in k_final -> 125us. Fixes:
//  (a) k_merge: pos >= CAP2 -> tier-3 list (grid-strided exact scan kernel).
//  (b) k_rechk2 stays KS2=32 (2-stage, low latency, proven in R21).
//  (c) k_mfma restructured: each wave owns a 256-code chunk -> NO barriers
//      in the K-loop; per-wave private 4KB LDS double-buffer with per-wave
//      s_waitcnt vmcnt(4); NSET=4 (64 px/wave) halves ds_read per CU.
//      One barrier + LDS reduce merges 4 waves (ascending order = first-
//      occurrence ties; near-ties flagged to tier-2 anyway).
// Tiers: tier-1 fp16 MARGIN1 6e-4 -> tier-2 hi/lo 6-MFMA (err ~1e-6) ->
// MARGIN2 3e-5 -> tier-3 exact fp32. Reference tie semantics preserved.
// Staging (R12): global_load_lds 16B registerless from pre-swizzled codebook.

#define NPIX 32768
#define NE   8192
#define EDIM 64
#define HW   4096
#define KSPLIT 8
#define CPS  (NE / KSPLIT)  // 1024 codes per split (tier-1)
#define NSTAGE 128          // tier-2 stage size
#define KS2  32
#define CPS2 (NE / KS2)     // 256 codes per split (tier-2)
#define NSTG2 (CPS2 / NSTAGE) // 2 stages (tier-2)
#define CAP2 8192           // max tier-2 items (overflow -> tier-3)
#define MARGIN1 6.0e-4f
#define MARGIN2 3.0e-5f
#define RSCL 2048.0f        // residual pre-scale (2^11)
#define RINV 4.8828125e-4f  // 2^-11

typedef _Float16 f16x8 __attribute__((ext_vector_type(8)));
typedef float f32x4  __attribute__((ext_vector_type(4)));

__device__ __forceinline__ short f2h_bits(float x) {
    _Float16 h = (_Float16)x;
    short s; __builtin_memcpy(&s, &h, 2); return s;
}
__device__ __forceinline__ float h_hi_f(float x) {
    return (float)(_Float16)x;
}
// map float to unsigned with same total order
__device__ __forceinline__ unsigned int order_u32(float f) {
    unsigned int s = __float_as_uint(f);
    return (s & 0x80000000u) ? ~s : (s | 0x80000000u);
}
// async global->LDS, 16B/lane; HW writes lane i at lds_base + i*16 (wave-uniform base)
__device__ __forceinline__ void gload_lds16(const void* g, void* l) {
    __builtin_amdgcn_global_load_lds(
        (const __attribute__((address_space(1))) void*)g,
        (__attribute__((address_space(3))) void*)l, 16, 0, 0);
}

// ---------------- prep (fused): codebook (swizzled fp16 hi + lo) + pixels ----
// esw/eswl layout: per 64-code group, 8 combos (sub[4] x {k0,k1}) x 1KB;
// within combo, MFMA-B fragment order: slot frag_lane=(o&3)*16+code_col holds
// 8 channels (16B). 32-code chunks are contiguous 4KB; 128-code stages 16KB.
__global__ __launch_bounds__(256) void k_prep(const float* __restrict__ emb,
                                              const float* __restrict__ z,
                                              float* __restrict__ e_norm,
                                              float* __restrict__ se_half,
                                              short* __restrict__ esw,
                                              short* __restrict__ eswl,
                                              float* __restrict__ zn,
                                              unsigned* __restrict__ counter) {
    if (blockIdx.x == 0 && threadIdx.x == 0) { counter[0] = 0u; counter[1] = 0u; }
    if (blockIdx.x < NE / 4) {
        // --- codebook: 1 code per wave, lane = channel ---
        const int wave = threadIdx.x >> 6;
        const int lane = threadIdx.x & 63;
        const int n = blockIdx.x * 4 + wave;
        float v = emb[n * EDIM + lane];
        float ss = v * v;
        #pragma unroll
        for (int off = 32; off; off >>= 1) ss += __shfl_xor(ss, off, 64);
        const float inv = 1.0f / fmaxf(sqrtf(ss), 1e-12f);
        const float en = v * inv;
        e_norm[n * EDIM + lane] = en;
        const float hf = h_hi_f(en);
        // swizzled fp16 write (c = lane)
        const int grp = n >> 6, cs = n & 63;
        const int sub = cs >> 4, colb = cs & 15;
        const int o = lane >> 3, j = lane & 7;     // o: khalf=o>>2, quad=o&3
        const int slot = ((o & 3) * 16 + colb) * 8 + j;
        const int off16 = grp * 4096 + (sub * 2 + (o >> 2)) * 512 + slot;
        esw[off16]  = f2h_bits(en);
        eswl[off16] = f2h_bits((en - hf) * RSCL);
        float s2 = en * en;
        #pragma unroll
        for (int off = 32; off; off >>= 1) s2 += __shfl_xor(s2, off, 64);
        if (lane == 0) se_half[n] = 0.5f * s2;
    } else {
        // --- pixels: single-pass normalize -> zn fp32 row-major [p][c] ---
        const int p = (blockIdx.x - NE / 4) * 256 + threadIdx.x;
        const int b = p >> 12, hw = p & (HW - 1);
        const float* zp = z + b * (EDIM * HW) + hw;
        float v[EDIM];
        #pragma unroll
        for (int c = 0; c < EDIM; ++c) v[c] = zp[c * HW];
        float ss = 0.0f;
        #pragma unroll
        for (int c = 0; c < EDIM; ++c) ss = fmaf(v[c], v[c], ss);
        const float inv = 1.0f / fmaxf(sqrtf(ss), 1e-12f);
        #pragma unroll
        for (int c4 = 0; c4 < 16; ++c4) {
            float4 o;
            o.x = v[c4 * 4 + 0] * inv;
            o.y = v[c4 * 4 + 1] * inv;
            o.z = v[c4 * 4 + 2] * inv;
            o.w = v[c4 * 4 + 3] * inv;
            *(float4*)(zn + p * EDIM + c4 * 4) = o;
        }
    }
}

// ---------------- tier-1 k_mfma: barrier-free wave-private split-K ----------
// Block: 4 waves x 64 pixels (same pixels); wave w owns codes
// [kbase + w*256, +256): 8 stages of 32 codes, private LDS dbuf, per-wave
// counted vmcnt -> NO barrier in the K-loop. v = dot + 2 in [1,3];
// 6-bit id (w<<4 | nb<<1 | sub) in low mantissa bits -> code = kbase+id*16+col.
// End: intra-wave col-merge, then one barrier + LDS cross-wave reduce
// (ascending wave order = ascending codes; strict > keeps earliest).
__global__ __launch_bounds__(256, 1) void k_mfma(const float* __restrict__ zn,
                                                 const short* __restrict__ esw,
                                                 float2* __restrict__ pv,   // [g][p] {b1,b2}
                                                 unsigned* __restrict__ pi) // [g][p] i1
{
    __shared__ __align__(16) short es[4][2][2048];   // [wave][buf][4KB] = 32KB
    __shared__ float s_b1[4][64], s_b2[4][64];
    __shared__ int   s_i1[4][64];

    const int tid  = threadIdx.x;
    const int w    = tid >> 6, lane = tid & 63;
    const int quad = lane >> 4, col = lane & 15;
    const int p0   = blockIdx.x * 64;               // block's 64 pixels
    const int g    = blockIdx.y;                    // codebook eighth
    const int kbase = g * CPS;
    const int cbase = kbase + w * 256;              // wave's code chunk

    // A fragments: 4 sets of 16 pixels (same for all waves); fp32 -> fp16
    f16x8 ah[4][2];
    #pragma unroll
    for (int s = 0; s < 4; ++s) {
        const float* zr = zn + (p0 + s * 16 + col) * EDIM;
        #pragma unroll
        for (int kc = 0; kc < 2; ++kc) {
            float f[8];
            *(float4*)(f + 0) = *(const float4*)(zr + kc * 32 + quad * 8 + 0);
            *(float4*)(f + 4) = *(const float4*)(zr + kc * 32 + quad * 8 + 4);
            #pragma unroll
            for (int i = 0; i < 8; ++i) ah[s][kc][i] = (_Float16)f[i];
        }
    }

    // top-2 state in max-space; values stuffed with 6-bit id; b1 >= b2
    float b1[4][4], b2[4][4];
    #pragma unroll
    for (int s = 0; s < 4; ++s)
        #pragma unroll
        for (int r = 0; r < 4; ++r) { b1[s][r] = 0.0f; b2[s][r] = 0.0f; }

    const f32x4 cini = {2.0f, 2.0f, 2.0f, 2.0f};   // |z|=|e|=1 -> bias constant

    // wave-private staging: per code 128B; 32-code stage = contiguous 4KB
    const char* gw = (const char*)esw + (size_t)cbase * 128 + lane * 16;
    // prologue: stage 0 -> buf 0 (4 x 1KB)
    #pragma unroll
    for (int it = 0; it < 4; ++it)
        gload_lds16(gw + it * 1024, (char*)&es[w][0][0] + it * 1024);

    for (int nb = 0; nb < 8; ++nb) {
        const int cur = nb & 1;
        if (nb + 1 < 8) {
            const char* gs = gw + (size_t)(nb + 1) * 4096;
            #pragma unroll
            for (int it = 0; it < 4; ++it)
                gload_lds16(gs + it * 1024, (char*)&es[w][cur ^ 1][0] + it * 1024);
            asm volatile("s_waitcnt vmcnt(4)" ::: "memory");  // stage-nb landed
        } else {
            asm volatile("s_waitcnt vmcnt(0)" ::: "memory");
        }
        __builtin_amdgcn_sched_barrier(0);

        const short* esb = &es[w][cur][0];
        #pragma unroll
        for (int sub = 0; sub < 2; ++sub) {      // 2 subtiles of 16 codes
            const short* base = esb + sub * 1024;
            const f16x8 bh0 = *(const f16x8*)(base + lane * 8);
            const f16x8 bh1 = *(const f16x8*)(base + 512 + lane * 8);
            const unsigned sid = (unsigned)((w << 4) | (nb << 1) | sub);
            #pragma unroll
            for (int s = 0; s < 4; ++s) {
                f32x4 acc;
                acc = __builtin_amdgcn_mfma_f32_16x16x32_f16(ah[s][0], bh0, cini, 0, 0, 0);
                acc = __builtin_amdgcn_mfma_f32_16x16x32_f16(ah[s][1], bh1, acc, 0, 0, 0);
                #pragma unroll
                for (int r = 0; r < 4; ++r) {
                    // stuff candidate id into low mantissa bits (v_and_or_b32)
                    const float v = __uint_as_float(
                        (__float_as_uint(acc[r]) & 0xFFFFFFC0u) | sid);
                    b2[s][r] = __builtin_amdgcn_fmed3f(v, b2[s][r], b1[s][r]);
                    b1[s][r] = fmaxf(b1[s][r], v);
                }
            }
        }
    }

    // recover winning index from stuffed id (col is lane-implicit)
    int i1[4][4];
    #pragma unroll
    for (int s = 0; s < 4; ++s)
        #pragma unroll
        for (int r = 0; r < 4; ++r) {
            const unsigned id6 = __float_as_uint(b1[s][r]) & 63u;
            i1[s][r] = kbase + (int)(id6 << 4) + col;
        }

    // intra-wave merge across the 16 col-lanes
    #pragma unroll
    for (int m = 1; m <= 8; m <<= 1) {
        #pragma unroll
        for (int s = 0; s < 4; ++s)
            #pragma unroll
            for (int r = 0; r < 4; ++r) {
                const float ob1 = __shfl_xor(b1[s][r], m, 64);
                const int   oi1 = __shfl_xor(i1[s][r], m, 64);
                const float ob2 = __shfl_xor(b2[s][r], m, 64);
                const bool take = (ob1 > b1[s][r]) || (ob1 == b1[s][r] && oi1 < i1[s][r]);
                b2[s][r] = fmaxf(fmaxf(b2[s][r], ob2), fminf(b1[s][r], ob1));
                b1[s][r] = take ? ob1 : b1[s][r];
                i1[s][r] = take ? oi1 : i1[s][r];
            }
    }
    // publish per-wave results
    if (col == 0) {
        #pragma unroll
        for (int s = 0; s < 4; ++s)
            #pragma unroll
            for (int r = 0; r < 4; ++r) {
                const int px = s * 16 + quad * 4 + r;   // C/D row = quad*4 + r
                s_b1[w][px] = b1[s][r];
                s_b2[w][px] = b2[s][r];
                s_i1[w][px] = i1[s][r];
            }
    }
    __syncthreads();
    // cross-wave reduce: wave 0, lane = pixel (ascending wave = ascending codes)
    if (w == 0) {
        float B1 = s_b1[0][lane], B2 = s_b2[0][lane];
        int   I1 = s_i1[0][lane];
        #pragma unroll
        for (int ww = 1; ww < 4; ++ww) {
            const float ob1 = s_b1[ww][lane], ob2 = s_b2[ww][lane];
            const int   oi1 = s_i1[ww][lane];
            const bool take = ob1 > B1;     // stuffed values distinct across waves
            B2 = fmaxf(fmaxf(B2, ob2), fminf(B1, ob1));
            B1 = take ? ob1 : B1;
            I1 = take ? oi1 : I1;
        }
        pv[g * NPIX + p0 + lane] = make_float2(B1, B2);
        pi[g * NPIX + p0 + lane] = (unsigned)I1;
    }
}

// ---------------- merge: combine KSPLIT partials, flag tier-2/tier-3 ---------
__global__ __launch_bounds__(256) void k_merge(const float2* __restrict__ pv,
                                               const unsigned* __restrict__ pi,
                                               unsigned* __restrict__ idx_arr,
                                               unsigned* __restrict__ list,
                                               unsigned* __restrict__ list2,
                                               unsigned* __restrict__ counter,
                                               unsigned long long* __restrict__ packed) {
    const int p = blockIdx.x * 256 + threadIdx.x;
    float2 v[KSPLIT]; unsigned ix[KSPLIT];
    #pragma unroll
    for (int gg = 0; gg < KSPLIT; ++gg) { v[gg] = pv[gg * NPIX + p]; ix[gg] = pi[gg * NPIX + p]; }
    // ascending group order + strict > == np first-occurrence tie semantics
    float b1 = v[0].x; unsigned i1 = ix[0]; int win = 0;
    #pragma unroll
    for (int gg = 1; gg < KSPLIT; ++gg)
        if (v[gg].x > b1) { b1 = v[gg].x; i1 = ix[gg]; win = gg; }
    float b2 = -3.0e38f;
    #pragma unroll
    for (int gg = 0; gg < KSPLIT; ++gg) {
        b2 = fmaxf(b2, v[gg].y);
        if (gg != win) b2 = fmaxf(b2, v[gg].x);
    }
    if (b1 - b2 < MARGIN1) {      // gap in v-space == gap in dist/2
        packed[p] = ~0ull;
        idx_arr[p] = i1 | 0x80000000u;
        const unsigned pos = atomicAdd(&counter[0], 1u);
        if (pos < CAP2) {
            list[pos] = p;        // tier-2
        } else {
            const unsigned q = atomicAdd(&counter[1], 1u);  // overflow -> tier-3
            if (q < NPIX) list2[q] = p;
        }
    } else {
        idx_arr[p] = i1;
    }
}

// ---------------- tier-2: hi/lo MFMA rescan of flagged pixels ---------------
// 32-way K-split (256 codes / block, 2 stages) for low per-block latency.
// Scoring: v = ah.bh + 2 + 2^-11*(al'.bh + ah.bl'), err ~1e-6. (R21-proven.)
__global__ __launch_bounds__(256, 1) void k_rechk2(const float* __restrict__ zn,
                                                   const short* __restrict__ esw,
                                                   const short* __restrict__ eswl,
                                                   const unsigned* __restrict__ list,
                                                   const unsigned* __restrict__ counter,
                                                   float2* __restrict__ pv,   // reused: [g2][item]
                                                   unsigned* __restrict__ pi) // reused: [g2][item]
{
    __shared__ __align__(16) short es[2][2][NSTAGE * EDIM];   // [buf][hi/lo] 16KB each

    int cnt = (int)counter[0]; if (cnt > CAP2) cnt = CAP2;
    const int ib = blockIdx.x * 128;          // item base for this block
    if (ib >= cnt) return;

    const int tid  = threadIdx.x;
    const int wave = tid >> 6, lane = tid & 63;
    const int quad = lane >> 4, col = lane & 15;
    const int g2   = blockIdx.y;
    const int kbase = g2 * CPS2;

    // A fragments: gathered pixel rows (clamped), fp16 hi + scaled residual lo
    f16x8 ah[2][2], al[2][2];
    #pragma unroll
    for (int s = 0; s < 2; ++s) {
        int item = ib + wave * 32 + s * 16 + col;
        if (item > cnt - 1) item = cnt - 1;
        const float* zr = zn + (size_t)list[item] * EDIM;
        #pragma unroll
        for (int kc = 0; kc < 2; ++kc) {
            float f[8];
            *(float4*)(f + 0) = *(const float4*)(zr + kc * 32 + quad * 8 + 0);
            *(float4*)(f + 4) = *(const float4*)(zr + kc * 32 + quad * 8 + 4);
            #pragma unroll
            for (int i = 0; i < 8; ++i) {
                ah[s][kc][i] = (_Float16)f[i];
                al[s][kc][i] = (_Float16)((f[i] - h_hi_f(f[i])) * RSCL);
            }
        }
    }

    float b1[2][4], b2[2][4]; int i1[2][4];
    #pragma unroll
    for (int s = 0; s < 2; ++s)
        #pragma unroll
        for (int r = 0; r < 4; ++r) { b1[s][r] = 0.0f; b2[s][r] = 0.0f; i1[s][r] = 0; }

    const f32x4 cini = {2.0f, 2.0f, 2.0f, 2.0f};
    const f32x4 zero = {0.0f, 0.0f, 0.0f, 0.0f};

    const int combo0 = wave * 4;
    const char* ghi0 = (const char*)esw  + (size_t)kbase * 128 + combo0 * 1024 + lane * 16;
    const char* glo0 = (const char*)eswl + (size_t)kbase * 128 + combo0 * 1024 + lane * 16;
    #pragma unroll
    for (int it = 0; it < 4; ++it) {
        gload_lds16(ghi0 + it * 1024, (char*)&es[0][0][0] + (combo0 + it) * 1024);
        gload_lds16(glo0 + it * 1024, (char*)&es[0][1][0] + (combo0 + it) * 1024);
    }

    for (int nb = 0; nb < NSTG2; ++nb) {
        const int cur = nb & 1;
        const int n0 = kbase + nb * NSTAGE;
        __syncthreads();
        if (nb + 1 < NSTG2) {
            const size_t soff = (size_t)(nb + 1) * (NSTAGE * EDIM * 2);
            #pragma unroll
            for (int it = 0; it < 4; ++it) {
                gload_lds16(ghi0 + soff + it * 1024,
                            (char*)&es[cur ^ 1][0][0] + (combo0 + it) * 1024);
                gload_lds16(glo0 + soff + it * 1024,
                            (char*)&es[cur ^ 1][1][0] + (combo0 + it) * 1024);
            }
        }

        const short* eh = es[cur][0];
        const short* el = es[cur][1];
        #pragma unroll
        for (int sub = 0; sub < 8; ++sub) {
            const f16x8 bh0 = *(const f16x8*)(eh + sub * 1024 + lane * 8);
            const f16x8 bh1 = *(const f16x8*)(eh + sub * 1024 + 512 + lane * 8);
            const f16x8 bl0 = *(const f16x8*)(el + sub * 1024 + lane * 8);
            const f16x8 bl1 = *(const f16x8*)(el + sub * 1024 + 512 + lane * 8);
            const int nglob = n0 + sub * 16 + col;
            #pragma unroll
            for (int s = 0; s < 2; ++s) {
                f32x4 acc;
                acc = __builtin_amdgcn_mfma_f32_16x16x32_f16(ah[s][0], bh0, cini, 0, 0, 0);
                acc = __builtin_amdgcn_mfma_f32_16x16x32_f16(ah[s][1], bh1, acc, 0, 0, 0);
                f32x4 cor;
                cor = __builtin_amdgcn_mfma_f32_16x16x32_f16(al[s][0], bh0, zero, 0, 0, 0);
                cor = __builtin_amdgcn_mfma_f32_16x16x32_f16(ah[s][0], bl0, cor, 0, 0, 0);
                cor = __builtin_amdgcn_mfma_f32_16x16x32_f16(al[s][1], bh1, cor, 0, 0, 0);
                cor = __builtin_amdgcn_mfma_f32_16x16x32_f16(ah[s][1], bl1, cor, 0, 0, 0);
                #pragma unroll
                for (int r = 0; r < 4; ++r) {
                    const float v = fmaf(cor[r], RINV, acc[r]);
                    b2[s][r] = __builtin_amdgcn_fmed3f(v, b2[s][r], b1[s][r]);
                    const bool t = v > b1[s][r];       // strict >, n ascending
                    b1[s][r] = fmaxf(b1[s][r], v);
                    i1[s][r] = t ? nglob : i1[s][r];
                }
            }
        }
    }

    // merge top-2 across the 16 col-lanes
    #pragma unroll
    for (int m = 1; m <= 8; m <<= 1) {
        #pragma unroll
        for (int s = 0; s < 2; ++s)
            #pragma unroll
            for (int r = 0; r < 4; ++r) {
                const float ob1 = __shfl_xor(b1[s][r], m, 64);
                const int   oi1 = __shfl_xor(i1[s][r], m, 64);
                const float ob2 = __shfl_xor(b2[s][r], m, 64);
                const bool take = (ob1 > b1[s][r]) || (ob1 == b1[s][r] && oi1 < i1[s][r]);
                b2[s][r] = fmaxf(fmaxf(b2[s][r], ob2), fminf(b1[s][r], ob1));
                b1[s][r] = take ? ob1 : b1[s][r];
                i1[s][r] = take ? oi1 : i1[s][r];
            }
    }
    if (col == 0) {
        #pragma unroll
        for (int s = 0; s < 2; ++s)
            #pragma unroll
            for (int r = 0; r < 4; ++r) {
                const int item = ib + wave * 32 + s * 16 + quad * 4 + r;
                if (item < cnt) {
                    pv[g2 * CAP2 + item] = make_float2(b1[s][r], b2[s][r]);
                    pi[g2 * CAP2 + item] = (unsigned)i1[s][r];
                }
            }
    }
}

// ---------------- tier-2b: merge tier-2 splits, resolve or escalate ----------
__global__ __launch_bounds__(256) void k_merge2(const float2* __restrict__ pv,
                                                const unsigned* __restrict__ pi,
                                                const unsigned* __restrict__ list,
                                                unsigned* __restrict__ counter,
                                                unsigned* __restrict__ list2,
                                                unsigned long long* __restrict__ packed) {
    const int item = blockIdx.x * 256 + threadIdx.x;
    int cnt = (int)counter[0]; if (cnt > CAP2) cnt = CAP2;
    if (item >= cnt) return;
    const unsigned p = list[item];
    float b1 = -3.0e38f, b2 = -3.0e38f; unsigned i1 = 0;
    #pragma unroll
    for (int g2 = 0; g2 < KS2; ++g2) {   // ascending split order: first-occurrence
        const float2 vv = pv[g2 * CAP2 + item];
        const unsigned ii = pi[g2 * CAP2 + item];
        if (vv.x > b1) { b2 = fmaxf(b2, b1); b1 = vv.x; i1 = ii; }
        else           { b2 = fmaxf(b2, vv.x); }
        b2 = fmaxf(b2, vv.y);
    }
    if (b1 - b2 < MARGIN2) {
        const unsigned q = atomicAdd(&counter[1], 1u);   // tier-3
        if (q < NPIX) list2[q] = p;
    } else {
        packed[p] = (unsigned long long)i1;   // final (high 32 = 0)
    }
}

// ---------------- tier-3: exact fp32 argmin (grid-strided, parallel) ---------
// item = (pixel, 512-code chunk). Coalesced: 4 codes x 16 lanes per b128
// (contiguous 1KB from L2-resident e_norm); 4 independent shfl-reduce chains.
__global__ __launch_bounds__(256) void k_recheck(const float* __restrict__ zn,
                                                 const float* __restrict__ e_norm,
                                                 const float* __restrict__ se_half,
                                                 const unsigned* __restrict__ list2,
                                                 const unsigned* __restrict__ counter,
                                                 unsigned long long* __restrict__ packed) {
    const int lane  = threadIdx.x & 63;
    const int k     = lane >> 4;        // code-in-group 0..3
    const int m     = lane & 15;        // c4 index 0..15
    const int wglob = (blockIdx.x * 256 + threadIdx.x) >> 6;
    const int nwav  = (gridDim.x * 256) >> 6;
    int cnt = (int)counter[1]; if (cnt > NPIX) cnt = NPIX;
    const int nitems = cnt * 16;
    const float4* e4 = (const float4*)e_norm;

    for (int item = wglob; item < nitems; item += nwav) {
        const int p     = (int)list2[item >> 4];
        const int chunk = item & 15;
        const float4 zv = *(const float4*)(zn + (size_t)p * EDIM + m * 4);
        float best = 3.0e38f; int bidx = 0;
        for (int t4 = 0; t4 < 32; ++t4) {              // 16 codes per iteration
            float s[4]; int n[4];
            #pragma unroll
            for (int j = 0; j < 4; ++j) {
                n[j] = chunk * 512 + (t4 * 4 + j) * 4 + k;
                const float4 ev = e4[n[j] * 16 + m];   // lane-linear: 1KB contiguous
                s[j] = fmaf(zv.w, ev.w, fmaf(zv.z, ev.z,
                       fmaf(zv.y, ev.y, zv.x * ev.x)));
            }
            #pragma unroll
            for (int j = 0; j < 4; ++j) s[j] += __shfl_xor(s[j], 1, 64);
            #pragma unroll
            for (int j = 0; j < 4; ++j) s[j] += __shfl_xor(s[j], 2, 64);
            #pragma unroll
            for (int j = 0; j < 4; ++j) s[j] += __shfl_xor(s[j], 4, 64);
            #pragma unroll
            for (int j = 0; j < 4; ++j) s[j] += __shfl_xor(s[j], 8, 64);
            #pragma unroll
            for (int j = 0; j < 4; ++j) {              // codes ascend over (t4,j)
                const float d = se_half[n[j]] - s[j];
                if (d < best) { best = d; bidx = n[j]; }
            }
        }
        #pragma unroll
        for (int mm = 1; mm <= 32; mm <<= 1) {         // wave first-min
            const float ob = __shfl_xor(best, mm, 64);
            const int   oi = __shfl_xor(bidx, mm, 64);
            if (ob < best || (ob == best && oi < bidx)) { best = ob; bidx = oi; }
        }
        if (lane == 0) {
            const unsigned long long key =
                ((unsigned long long)order_u32(best) << 32) | (unsigned)bidx;
            atomicMin(&packed[p], key);
        }
    }
}

// ---------------- finalize: write indices + gather z_q (4 thr/pixel) ---------
__global__ __launch_bounds__(256) void k_finalize(const unsigned* __restrict__ idx_arr,
                                                  const unsigned long long* __restrict__ packed,
                                                  const float* __restrict__ e_norm,
                                                  float* __restrict__ out) {
    const int pl = threadIdx.x & 63;
    const int q  = threadIdx.x >> 6;                  // channel quarter 0..3
    const int p  = blockIdx.x * 64 + pl;
    const unsigned v = idx_arr[p];
    const int bidx = (v & 0x80000000u) ? (int)(packed[p] & 0xFFFFFFFFull)
                                       : (int)v;
    if (q == 0) out[NPIX * EDIM + p] = (float)bidx;
    const int b = p >> 12, hw = p & (HW - 1);
    float* op = out + b * (EDIM * HW) + hw;
    const float4* ep4 = (const float4*)(e_norm + (size_t)bidx * EDIM + q * 16);
    #pragma unroll
    for (int j = 0; j < 4; ++j) {
        const float4 e = ep4[j];
        const int c = q * 16 + j * 4;
        op[(c + 0) * HW] = e.x; op[(c + 1) * HW] = e.y;   // coalesced per c
        op[(c + 2) * HW] = e.z; op[(c + 3) * HW] = e.w;
    }
}

extern "C" void kernel_launch(void* const* d_in, const int* in_sizes, int n_in,
                              void* d_out, int out_size, void* d_ws, size_t ws_size,
                              hipStream_t stream) {
    const float* z   = (const float*)d_in[0];
    const float* emb = (const float*)d_in[1];
    float* out = (float*)d_out;

    // workspace layout (~15.7 MB)
    float* e_norm  = (float*)d_ws;                       // 2 MB
    float* se_half = e_norm + NE * EDIM;                 // 32 KB
    short* esw  = (short*)(se_half + NE);                // 1 MB (swizzled fp16 hi)
    short* eswl = esw + NE * EDIM;                       // 1 MB (swizzled fp16 lo)
    float* zn = (float*)(eswl + NE * EDIM);              // 8 MB
    unsigned* idx_arr = (unsigned*)(zn + NPIX * EDIM);   // 128 KB
    unsigned* list    = idx_arr + NPIX;                  // 128 KB (tier-2 items)
    unsigned* list2   = list + NPIX;                     // 128 KB (tier-3 pixels)
    unsigned* counter = list2 + NPIX;                    // 8 B (+pad)
    unsigned long long* packed = (unsigned long long*)(counter + 64); // 256 KB
    float2*   pv = (float2*)(packed + NPIX);             // 2 MB (8xNPIX == 32xCAP2)
    unsigned* pi = (unsigned*)(pv + KSPLIT * NPIX);      // 1 MB

    k_prep<<<NE / 4 + NPIX / 256, 256, 0, stream>>>(emb, z, e_norm, se_half,
                                                    esw, eswl, zn, counter);
    k_mfma<<<dim3(NPIX / 64, KSPLIT), 256, 0, stream>>>(zn, esw, pv, pi);
    k_merge<<<NPIX / 256, 256, 0, stream>>>(pv, pi, idx_arr, list, list2,
                                            counter, packed);
    k_rechk2<<<dim3(CAP2 / 128, KS2), 256, 0, stream>>>(zn, esw, eswl, list,
                                                        counter, pv, pi);
    k_merge2<<<CAP2 / 256, 256, 0, stream>>>(pv, pi, list, counter, list2, packed);
    k_recheck<<<1024, 256, 0, stream>>>(zn, e_norm, se_half, list2, counter, packed);
    k_finalize<<<NPIX / 64, 256, 0, stream>>>(idx_arr, packed, e_norm, out);
}

// Round 10
// 189.272 us; speedup vs baseline: 1.5821x; 1.3148x over previous
//
#include <hip/hip_runtime.h>

// VectorQuantizer: z [8,64,64,64] fp32 (BCHW), embedding [8192,64] fp32.
// Outputs (concat): z_q [8,64,64,64] fp32 (BCHW), indices [32768] as fp32.
//
// R23: tier-1 reverted to R19-proven form (75.4us); tier-2 resized so the
// expensive tier-3 VALU scan is ~empty.
// R22 post-mortem: barrier-free wave-private k_mfma regressed (116.8us) --
// 4x redundant A-fragment load/convert per block swamped barrier savings.
// Barrier edits 0-for-3 (R16/R20/R22): R19 2-phase __syncthreads stands.
// Flag count is ~12-20K (R21 overflow proved >8192), so:
//   tier-2: KS2=16 splits, CAP2=16384 (16xCAP2 == 8xNPIX, exact pv/pi fit),
//           64-code stages (32KB LDS, ~3-4 blocks/CU), early-exit grid.
//   overflow pos >= CAP2 -> tier-3 grid-strided exact scan (expected ~0).
// Tiers: tier-1 fp16 MARGIN1 6e-4 -> tier-2 hi/lo 6-MFMA (err ~1e-6) ->
// MARGIN2 3e-5 -> tier-3 exact fp32. Reference tie semantics preserved
// (ascending split order, strict >, first-min).
// Selection (R14): 6-bit candidate id in low mantissa bits (tier-1 only).
// Staging (R12): global_load_lds 16B registerless from pre-swizzled codebook.

#define NPIX 32768
#define NE   8192
#define EDIM 64
#define HW   4096
#define NSTAGE 128          // tier-1: codes per LDS stage (8 subtiles of 16)
#define KSPLIT 8
#define CPS  (NE / KSPLIT)  // 1024 codes per split (tier-1)
#define NSTG (CPS / NSTAGE) // 8 stages per block (tier-1)
#define KS2  16
#define CPS2 (NE / KS2)     // 512 codes per split (tier-2)
#define NST2 64             // tier-2: codes per stage
#define NSTG2 (CPS2 / NST2) // 8 stages (tier-2)
#define CAP2 16384          // max tier-2 items (16*CAP2 == 8*NPIX)
#define MARGIN1 6.0e-4f
#define MARGIN2 3.0e-5f
#define NSET 2              // row-sets of 16 pixels per wave (PPW=32)
#define RSCL 2048.0f        // residual pre-scale (2^11)
#define RINV 4.8828125e-4f  // 2^-11

typedef _Float16 f16x8 __attribute__((ext_vector_type(8)));
typedef float f32x4  __attribute__((ext_vector_type(4)));

__device__ __forceinline__ short f2h_bits(float x) {
    _Float16 h = (_Float16)x;
    short s; __builtin_memcpy(&s, &h, 2); return s;
}
__device__ __forceinline__ float h_hi_f(float x) {
    return (float)(_Float16)x;
}
// map float to unsigned with same total order
__device__ __forceinline__ unsigned int order_u32(float f) {
    unsigned int s = __float_as_uint(f);
    return (s & 0x80000000u) ? ~s : (s | 0x80000000u);
}
// async global->LDS, 16B/lane; HW writes lane i at lds_base + i*16 (wave-uniform base)
__device__ __forceinline__ void gload_lds16(const void* g, void* l) {
    __builtin_amdgcn_global_load_lds(
        (const __attribute__((address_space(1))) void*)g,
        (__attribute__((address_space(3))) void*)l, 16, 0, 0);
}

// ---------------- prep (fused): codebook (swizzled fp16 hi + lo) + pixels ----
// esw/eswl layout: per 64-code group, 8 combos (sub[4] x {k0,k1}) x 1KB;
// within combo, MFMA-B fragment order: slot frag_lane=(o&3)*16+code_col holds
// 8 channels (16B). 64-code groups are contiguous 8KB; 128-code stages 16KB.
__global__ __launch_bounds__(256) void k_prep(const float* __restrict__ emb,
                                              const float* __restrict__ z,
                                              float* __restrict__ e_norm,
                                              float* __restrict__ se_half,
                                              short* __restrict__ esw,
                                              short* __restrict__ eswl,
                                              float* __restrict__ zn,
                                              unsigned* __restrict__ counter) {
    if (blockIdx.x == 0 && threadIdx.x == 0) { counter[0] = 0u; counter[1] = 0u; }
    if (blockIdx.x < NE / 4) {
        // --- codebook: 1 code per wave, lane = channel ---
        const int wave = threadIdx.x >> 6;
        const int lane = threadIdx.x & 63;
        const int n = blockIdx.x * 4 + wave;
        float v = emb[n * EDIM + lane];
        float ss = v * v;
        #pragma unroll
        for (int off = 32; off; off >>= 1) ss += __shfl_xor(ss, off, 64);
        const float inv = 1.0f / fmaxf(sqrtf(ss), 1e-12f);
        const float en = v * inv;
        e_norm[n * EDIM + lane] = en;
        const float hf = h_hi_f(en);
        // swizzled fp16 write (c = lane)
        const int grp = n >> 6, cs = n & 63;
        const int sub = cs >> 4, colb = cs & 15;
        const int o = lane >> 3, j = lane & 7;     // o: khalf=o>>2, quad=o&3
        const int slot = ((o & 3) * 16 + colb) * 8 + j;
        const int off16 = grp * 4096 + (sub * 2 + (o >> 2)) * 512 + slot;
        esw[off16]  = f2h_bits(en);
        eswl[off16] = f2h_bits((en - hf) * RSCL);
        float s2 = en * en;
        #pragma unroll
        for (int off = 32; off; off >>= 1) s2 += __shfl_xor(s2, off, 64);
        if (lane == 0) se_half[n] = 0.5f * s2;
    } else {
        // --- pixels: single-pass normalize -> zn fp32 row-major [p][c] ---
        const int p = (blockIdx.x - NE / 4) * 256 + threadIdx.x;
        const int b = p >> 12, hw = p & (HW - 1);
        const float* zp = z + b * (EDIM * HW) + hw;
        float v[EDIM];
        #pragma unroll
        for (int c = 0; c < EDIM; ++c) v[c] = zp[c * HW];
        float ss = 0.0f;
        #pragma unroll
        for (int c = 0; c < EDIM; ++c) ss = fmaf(v[c], v[c], ss);
        const float inv = 1.0f / fmaxf(sqrtf(ss), 1e-12f);
        #pragma unroll
        for (int c4 = 0; c4 < 16; ++c4) {
            float4 o;
            o.x = v[c4 * 4 + 0] * inv;
            o.y = v[c4 * 4 + 1] * inv;
            o.z = v[c4 * 4 + 2] * inv;
            o.w = v[c4 * 4 + 3] * inv;
            *(float4*)(zn + p * EDIM + c4 * 4) = o;
        }
    }
}

// ---------------- tier-1 k_mfma: split-K partial top-2 (R19 proven) ---------
// Block: 4 waves x 32 pixels = 128 pixels, one codebook eighth (blockIdx.y).
// v = dot + 2 in [1,3]; argmin dist == argmax v (unit vectors). Low 6 mantissa
// bits carry the candidate id (stage*8+sub). Layouts (HW-verified):
// A[m=lane&15][k=quad*8+j], B[k=quad*8+j][n=lane&15], C/D row=(lane>>4)*4+reg,
// col=lane&15.
__global__ __launch_bounds__(256, 1) void k_mfma(const float* __restrict__ zn,
                                                 const short* __restrict__ esw,
                                                 float2* __restrict__ pv,   // [g][p] {b1,b2} (max-space)
                                                 unsigned* __restrict__ pi) // [g][p] i1
{
    __shared__ __align__(16) short es[2][NSTAGE * EDIM];   // 2 x 16KB

    const int tid  = threadIdx.x;             // 0..255
    const int wave = tid >> 6, lane = tid & 63;
    const int quad = lane >> 4, col = lane & 15;
    const int p0   = blockIdx.x * 128 + wave * 32;  // wave's 32 pixels (2 sets)
    const int g    = blockIdx.y;                    // codebook eighth
    const int kbase = g * CPS;

    // A fragments: 2 sets of 16 pixels; fp32 zn -> fp16 (single product)
    f16x8 ah[NSET][2];
    #pragma unroll
    for (int s = 0; s < NSET; ++s) {
        const float* zr = zn + (p0 + s * 16 + col) * EDIM;
        #pragma unroll
        for (int kc = 0; kc < 2; ++kc) {
            float f[8];
            *(float4*)(f + 0) = *(const float4*)(zr + kc * 32 + quad * 8 + 0);
            *(float4*)(f + 4) = *(const float4*)(zr + kc * 32 + quad * 8 + 4);
            #pragma unroll
            for (int i = 0; i < 8; ++i) ah[s][kc][i] = (_Float16)f[i];
        }
    }

    // top-2 state in max-space; values stuffed with 6-bit id; b1 >= b2 invariant
    float b1[NSET][4], b2[NSET][4];
    #pragma unroll
    for (int s = 0; s < NSET; ++s)
        #pragma unroll
        for (int r = 0; r < 4; ++r) { b1[s][r] = 0.0f; b2[s][r] = 0.0f; }

    const f32x4 cini = {2.0f, 2.0f, 2.0f, 2.0f};   // |z|=|e|=1 -> bias constant

    // this wave's staging window: src and dst are both uniform + lane*16
    const int combo0 = wave * 4;   // 16 combos x 1KB per 16KB stage
    const char* gsrc0 = (const char*)esw + (size_t)kbase * 128
                        + combo0 * 1024 + lane * 16;
    // prologue: issue stage 0 -> buf 0
    #pragma unroll
    for (int it = 0; it < 4; ++it)
        gload_lds16(gsrc0 + it * 1024, (char*)&es[0][0] + (combo0 + it) * 1024);

    for (int nb = 0; nb < NSTG; ++nb) {
        const int cur = nb & 1;
        __syncthreads();   // vmcnt drained: buf[cur] complete; buf[cur^1] reusable
        if (nb + 1 < NSTG) {
            const char* gsrc = gsrc0 + (size_t)(nb + 1) * (NSTAGE * EDIM * 2);
            #pragma unroll
            for (int it = 0; it < 4; ++it)
                gload_lds16(gsrc + it * 1024,
                            (char*)&es[cur ^ 1][0] + (combo0 + it) * 1024);
        }

        const short* esb = es[cur];
        #pragma unroll
        for (int sub = 0; sub < 8; ++sub) {       // 8 subtiles of 16 codes
            const short* base = esb + sub * 1024;
            const f16x8 bh0 = *(const f16x8*)(base + lane * 8);
            const f16x8 bh1 = *(const f16x8*)(base + 512 + lane * 8);
            const unsigned sid = (unsigned)((nb << 3) | sub);  // 6-bit id, uniform
            #pragma unroll
            for (int s = 0; s < NSET; ++s) {
                // 2-deep chain seeded with C = {2.0}
                f32x4 acc;
                acc = __builtin_amdgcn_mfma_f32_16x16x32_f16(ah[s][0], bh0, cini, 0, 0, 0);
                acc = __builtin_amdgcn_mfma_f32_16x16x32_f16(ah[s][1], bh1, acc, 0, 0, 0);
                #pragma unroll
                for (int r = 0; r < 4; ++r) {
                    // stuff candidate id into low mantissa bits (v_and_or_b32)
                    const float v = __uint_as_float(
                        (__float_as_uint(acc[r]) & 0xFFFFFFC0u) | sid);
                    // b1>=b2 invariant -> med3 == new 2nd-max; then running max
                    b2[s][r] = __builtin_amdgcn_fmed3f(v, b2[s][r], b1[s][r]);
                    b1[s][r] = fmaxf(b1[s][r], v);
                }
            }
        }
    }

    // recover winning index from b1's stuffed id (col is lane-implicit)
    int i1[NSET][4];
    #pragma unroll
    for (int s = 0; s < NSET; ++s)
        #pragma unroll
        for (int r = 0; r < 4; ++r) {
            const unsigned id6 = __float_as_uint(b1[s][r]) & 63u;
            i1[s][r] = kbase + (int)(id6 << 4) + col;
        }

    // merge top-2 across the 16 col-lanes (xor 1,2,4,8 stays inside quad group)
    #pragma unroll
    for (int m = 1; m <= 8; m <<= 1) {
        #pragma unroll
        for (int s = 0; s < NSET; ++s)
            #pragma unroll
            for (int r = 0; r < 4; ++r) {
                const float ob1 = __shfl_xor(b1[s][r], m, 64);
                const int   oi1 = __shfl_xor(i1[s][r], m, 64);
                const float ob2 = __shfl_xor(b2[s][r], m, 64);
                const bool take = (ob1 > b1[s][r]) || (ob1 == b1[s][r] && oi1 < i1[s][r]);
                b2[s][r] = fmaxf(fmaxf(b2[s][r], ob2), fminf(b1[s][r], ob1));
                b1[s][r] = take ? ob1 : b1[s][r];
                i1[s][r] = take ? oi1 : i1[s][r];
            }
    }
    if (col == 0) {
        #pragma unroll
        for (int s = 0; s < NSET; ++s)
            #pragma unroll
            for (int r = 0; r < 4; ++r) {
                const int p = p0 + s * 16 + quad * 4 + r;   // C/D row = quad*4 + r
                pv[g * NPIX + p] = make_float2(b1[s][r], b2[s][r]);
                pi[g * NPIX + p] = (unsigned)i1[s][r];
            }
    }
}

// ---------------- merge: combine KSPLIT partials, flag tier-2/tier-3 ---------
__global__ __launch_bounds__(256) void k_merge(const float2* __restrict__ pv,
                                               const unsigned* __restrict__ pi,
                                               unsigned* __restrict__ idx_arr,
                                               unsigned* __restrict__ list,
                                               unsigned* __restrict__ list2,
                                               unsigned* __restrict__ counter,
                                               unsigned long long* __restrict__ packed) {
    const int p = blockIdx.x * 256 + threadIdx.x;
    float2 v[KSPLIT]; unsigned ix[KSPLIT];
    #pragma unroll
    for (int gg = 0; gg < KSPLIT; ++gg) { v[gg] = pv[gg * NPIX + p]; ix[gg] = pi[gg * NPIX + p]; }
    // ascending group order + strict > == np first-occurrence tie semantics
    float b1 = v[0].x; unsigned i1 = ix[0]; int win = 0;
    #pragma unroll
    for (int gg = 1; gg < KSPLIT; ++gg)
        if (v[gg].x > b1) { b1 = v[gg].x; i1 = ix[gg]; win = gg; }
    float b2 = -3.0e38f;
    #pragma unroll
    for (int gg = 0; gg < KSPLIT; ++gg) {
        b2 = fmaxf(b2, v[gg].y);
        if (gg != win) b2 = fmaxf(b2, v[gg].x);
    }
    if (b1 - b2 < MARGIN1) {      // gap in v-space == gap in dist/2
        packed[p] = ~0ull;
        idx_arr[p] = i1 | 0x80000000u;
        const unsigned pos = atomicAdd(&counter[0], 1u);
        if (pos < CAP2) {
            list[pos] = p;        // tier-2
        } else {
            const unsigned q = atomicAdd(&counter[1], 1u);  // overflow -> tier-3
            if (q < NPIX) list2[q] = p;
        }
    } else {
        idx_arr[p] = i1;
    }
}

// ---------------- tier-2: hi/lo MFMA rescan of flagged pixels ---------------
// 16-way K-split (512 codes / block, 8 stages of 64 codes, 32KB LDS).
// Scoring: v = ah.bh + 2 + 2^-11*(al'.bh + ah.bl'), err ~1e-6.
__global__ __launch_bounds__(256, 1) void k_rechk2(const float* __restrict__ zn,
                                                   const short* __restrict__ esw,
                                                   const short* __restrict__ eswl,
                                                   const unsigned* __restrict__ list,
                                                   const unsigned* __restrict__ counter,
                                                   float2* __restrict__ pv,   // reused: [g2][item]
                                                   unsigned* __restrict__ pi) // reused: [g2][item]
{
    __shared__ __align__(16) short es[2][2][NST2 * EDIM];   // [buf][hi/lo] 8KB each

    int cnt = (int)counter[0]; if (cnt > CAP2) cnt = CAP2;
    const int ib = blockIdx.x * 128;          // item base for this block
    if (ib >= cnt) return;

    const int tid  = threadIdx.x;
    const int wave = tid >> 6, lane = tid & 63;
    const int quad = lane >> 4, col = lane & 15;
    const int g2   = blockIdx.y;
    const int kbase = g2 * CPS2;

    // A fragments: gathered pixel rows (clamped), fp16 hi + scaled residual lo
    f16x8 ah[NSET][2], al[NSET][2];
    #pragma unroll
    for (int s = 0; s < NSET; ++s) {
        int item = ib + wave * 32 + s * 16 + col;
        if (item > cnt - 1) item = cnt - 1;
        const float* zr = zn + (size_t)list[item] * EDIM;
        #pragma unroll
        for (int kc = 0; kc < 2; ++kc) {
            float f[8];
            *(float4*)(f + 0) = *(const float4*)(zr + kc * 32 + quad * 8 + 0);
            *(float4*)(f + 4) = *(const float4*)(zr + kc * 32 + quad * 8 + 4);
            #pragma unroll
            for (int i = 0; i < 8; ++i) {
                ah[s][kc][i] = (_Float16)f[i];
                al[s][kc][i] = (_Float16)((f[i] - h_hi_f(f[i])) * RSCL);
            }
        }
    }

    float b1[NSET][4], b2[NSET][4]; int i1[NSET][4];
    #pragma unroll
    for (int s = 0; s < NSET; ++s)
        #pragma unroll
        for (int r = 0; r < 4; ++r) { b1[s][r] = 0.0f; b2[s][r] = 0.0f; i1[s][r] = 0; }

    const f32x4 cini = {2.0f, 2.0f, 2.0f, 2.0f};
    const f32x4 zero = {0.0f, 0.0f, 0.0f, 0.0f};

    // wave stages 1 hi combo + 1 lo combo per 8KB stage (8 combos each)
    const int combo0 = wave * 2;   // 8 combos x 1KB per 8KB stage
    const char* ghi0 = (const char*)esw  + (size_t)kbase * 128 + combo0 * 1024 + lane * 16;
    const char* glo0 = (const char*)eswl + (size_t)kbase * 128 + combo0 * 1024 + lane * 16;
    #pragma unroll
    for (int it = 0; it < 2; ++it) {
        gload_lds16(ghi0 + it * 1024, (char*)&es[0][0][0] + (combo0 + it) * 1024);
        gload_lds16(glo0 + it * 1024, (char*)&es[0][1][0] + (combo0 + it) * 1024);
    }

    for (int nb = 0; nb < NSTG2; ++nb) {
        const int cur = nb & 1;
        const int n0 = kbase + nb * NST2;
        __syncthreads();
        if (nb + 1 < NSTG2) {
            const size_t soff = (size_t)(nb + 1) * (NST2 * EDIM * 2);
            #pragma unroll
            for (int it = 0; it < 2; ++it) {
                gload_lds16(ghi0 + soff + it * 1024,
                            (char*)&es[cur ^ 1][0][0] + (combo0 + it) * 1024);
                gload_lds16(glo0 + soff + it * 1024,
                            (char*)&es[cur ^ 1][1][0] + (combo0 + it) * 1024);
            }
        }

        const short* eh = es[cur][0];
        const short* el = es[cur][1];
        #pragma unroll
        for (int sub = 0; sub < 4; ++sub) {       // 4 subtiles of 16 codes
            const f16x8 bh0 = *(const f16x8*)(eh + sub * 1024 + lane * 8);
            const f16x8 bh1 = *(const f16x8*)(eh + sub * 1024 + 512 + lane * 8);
            const f16x8 bl0 = *(const f16x8*)(el + sub * 1024 + lane * 8);
            const f16x8 bl1 = *(const f16x8*)(el + sub * 1024 + 512 + lane * 8);
            const int nglob = n0 + sub * 16 + col;
            #pragma unroll
            for (int s = 0; s < NSET; ++s) {
                f32x4 acc;
                acc = __builtin_amdgcn_mfma_f32_16x16x32_f16(ah[s][0], bh0, cini, 0, 0, 0);
                acc = __builtin_amdgcn_mfma_f32_16x16x32_f16(ah[s][1], bh1, acc, 0, 0, 0);
                f32x4 cor;
                cor = __builtin_amdgcn_mfma_f32_16x16x32_f16(al[s][0], bh0, zero, 0, 0, 0);
                cor = __builtin_amdgcn_mfma_f32_16x16x32_f16(ah[s][0], bl0, cor, 0, 0, 0);
                cor = __builtin_amdgcn_mfma_f32_16x16x32_f16(al[s][1], bh1, cor, 0, 0, 0);
                cor = __builtin_amdgcn_mfma_f32_16x16x32_f16(ah[s][1], bl1, cor, 0, 0, 0);
                #pragma unroll
                for (int r = 0; r < 4; ++r) {
                    const float v = fmaf(cor[r], RINV, acc[r]);
                    b2[s][r] = __builtin_amdgcn_fmed3f(v, b2[s][r], b1[s][r]);
                    const bool t = v > b1[s][r];       // strict >, n ascending
                    b1[s][r] = fmaxf(b1[s][r], v);
                    i1[s][r] = t ? nglob : i1[s][r];
                }
            }
        }
    }

    // merge top-2 across the 16 col-lanes
    #pragma unroll
    for (int m = 1; m <= 8; m <<= 1) {
        #pragma unroll
        for (int s = 0; s < NSET; ++s)
            #pragma unroll
            for (int r = 0; r < 4; ++r) {
                const float ob1 = __shfl_xor(b1[s][r], m, 64);
                const int   oi1 = __shfl_xor(i1[s][r], m, 64);
                const float ob2 = __shfl_xor(b2[s][r], m, 64);
                const bool take = (ob1 > b1[s][r]) || (ob1 == b1[s][r] && oi1 < i1[s][r]);
                b2[s][r] = fmaxf(fmaxf(b2[s][r], ob2), fminf(b1[s][r], ob1));
                b1[s][r] = take ? ob1 : b1[s][r];
                i1[s][r] = take ? oi1 : i1[s][r];
            }
    }
    if (col == 0) {
        #pragma unroll
        for (int s = 0; s < NSET; ++s)
            #pragma unroll
            for (int r = 0; r < 4; ++r) {
                const int item = ib + wave * 32 + s * 16 + quad * 4 + r;
                if (item < cnt) {
                    pv[g2 * CAP2 + item] = make_float2(b1[s][r], b2[s][r]);
                    pi[g2 * CAP2 + item] = (unsigned)i1[s][r];
                }
            }
    }
}

// ---------------- tier-2b: merge tier-2 splits, resolve or escalate ----------
__global__ __launch_bounds__(256) void k_merge2(const float2* __restrict__ pv,
                                                const unsigned* __restrict__ pi,
                                                const unsigned* __restrict__ list,
                                                unsigned* __restrict__ counter,
                                                unsigned* __restrict__ list2,
                                                unsigned long long* __restrict__ packed) {
    const int item = blockIdx.x * 256 + threadIdx.x;
    int cnt = (int)counter[0]; if (cnt > CAP2) cnt = CAP2;
    if (item >= cnt) return;
    const unsigned p = list[item];
    float b1 = -3.0e38f, b2 = -3.0e38f; unsigned i1 = 0;
    #pragma unroll
    for (int g2 = 0; g2 < KS2; ++g2) {   // ascending split order: first-occurrence
        const float2 vv = pv[g2 * CAP2 + item];
        const unsigned ii = pi[g2 * CAP2 + item];
        if (vv.x > b1) { b2 = fmaxf(b2, b1); b1 = vv.x; i1 = ii; }
        else           { b2 = fmaxf(b2, vv.x); }
        b2 = fmaxf(b2, vv.y);
    }
    if (b1 - b2 < MARGIN2) {
        const unsigned q = atomicAdd(&counter[1], 1u);   // tier-3
        if (q < NPIX) list2[q] = p;
    } else {
        packed[p] = (unsigned long long)i1;   // final (high 32 = 0)
    }
}

// ---------------- tier-3: exact fp32 argmin (grid-strided, parallel) ---------
// item = (pixel, 512-code chunk). Coalesced: 4 codes x 16 lanes per b128
// (contiguous 1KB from L2-resident e_norm); 4 independent shfl-reduce chains.
__global__ __launch_bounds__(256) void k_recheck(const float* __restrict__ zn,
                                                 const float* __restrict__ e_norm,
                                                 const float* __restrict__ se_half,
                                                 const unsigned* __restrict__ list2,
                                                 const unsigned* __restrict__ counter,
                                                 unsigned long long* __restrict__ packed) {
    const int lane  = threadIdx.x & 63;
    const int k     = lane >> 4;        // code-in-group 0..3
    const int m     = lane & 15;        // c4 index 0..15
    const int wglob = (blockIdx.x * 256 + threadIdx.x) >> 6;
    const int nwav  = (gridDim.x * 256) >> 6;
    int cnt = (int)counter[1]; if (cnt > NPIX) cnt = NPIX;
    const int nitems = cnt * 16;
    const float4* e4 = (const float4*)e_norm;

    for (int item = wglob; item < nitems; item += nwav) {
        const int p     = (int)list2[item >> 4];
        const int chunk = item & 15;
        const float4 zv = *(const float4*)(zn + (size_t)p * EDIM + m * 4);
        float best = 3.0e38f; int bidx = 0;
        for (int t4 = 0; t4 < 32; ++t4) {              // 16 codes per iteration
            float s[4]; int n[4];
            #pragma unroll
            for (int j = 0; j < 4; ++j) {
                n[j] = chunk * 512 + (t4 * 4 + j) * 4 + k;
                const float4 ev = e4[n[j] * 16 + m];   // lane-linear: 1KB contiguous
                s[j] = fmaf(zv.w, ev.w, fmaf(zv.z, ev.z,
                       fmaf(zv.y, ev.y, zv.x * ev.x)));
            }
            #pragma unroll
            for (int j = 0; j < 4; ++j) s[j] += __shfl_xor(s[j], 1, 64);
            #pragma unroll
            for (int j = 0; j < 4; ++j) s[j] += __shfl_xor(s[j], 2, 64);
            #pragma unroll
            for (int j = 0; j < 4; ++j) s[j] += __shfl_xor(s[j], 4, 64);
            #pragma unroll
            for (int j = 0; j < 4; ++j) s[j] += __shfl_xor(s[j], 8, 64);
            #pragma unroll
            for (int j = 0; j < 4; ++j) {              // codes ascend over (t4,j)
                const float d = se_half[n[j]] - s[j];
                if (d < best) { best = d; bidx = n[j]; }
            }
        }
        #pragma unroll
        for (int mm = 1; mm <= 32; mm <<= 1) {         // wave first-min
            const float ob = __shfl_xor(best, mm, 64);
            const int   oi = __shfl_xor(bidx, mm, 64);
            if (ob < best || (ob == best && oi < bidx)) { best = ob; bidx = oi; }
        }
        if (lane == 0) {
            const unsigned long long key =
                ((unsigned long long)order_u32(best) << 32) | (unsigned)bidx;
            atomicMin(&packed[p], key);
        }
    }
}

// ---------------- finalize: write indices + gather z_q (4 thr/pixel) ---------
__global__ __launch_bounds__(256) void k_finalize(const unsigned* __restrict__ idx_arr,
                                                  const unsigned long long* __restrict__ packed,
                                                  const float* __restrict__ e_norm,
                                                  float* __restrict__ out) {
    const int pl = threadIdx.x & 63;
    const int q  = threadIdx.x >> 6;                  // channel quarter 0..3
    const int p  = blockIdx.x * 64 + pl;
    const unsigned v = idx_arr[p];
    const int bidx = (v & 0x80000000u) ? (int)(packed[p] & 0xFFFFFFFFull)
                                       : (int)v;
    if (q == 0) out[NPIX * EDIM + p] = (float)bidx;
    const int b = p >> 12, hw = p & (HW - 1);
    float* op = out + b * (EDIM * HW) + hw;
    const float4* ep4 = (const float4*)(e_norm + (size_t)bidx * EDIM + q * 16);
    #pragma unroll
    for (int j = 0; j < 4; ++j) {
        const float4 e = ep4[j];
        const int c = q * 16 + j * 4;
        op[(c + 0) * HW] = e.x; op[(c + 1) * HW] = e.y;   // coalesced per c
        op[(c + 2) * HW] = e.z; op[(c + 3) * HW] = e.w;
    }
}

extern "C" void kernel_launch(void* const* d_in, const int* in_sizes, int n_in,
                              void* d_out, int out_size, void* d_ws, size_t ws_size,
                              hipStream_t stream) {
    const float* z   = (const float*)d_in[0];
    const float* emb = (const float*)d_in[1];
    float* out = (float*)d_out;

    // workspace layout (~15.7 MB)
    float* e_norm  = (float*)d_ws;                       // 2 MB
    float* se_half = e_norm + NE * EDIM;                 // 32 KB
    short* esw  = (short*)(se_half + NE);                // 1 MB (swizzled fp16 hi)
    short* eswl = esw + NE * EDIM;                       // 1 MB (swizzled fp16 lo)
    float* zn = (float*)(eswl + NE * EDIM);              // 8 MB
    unsigned* idx_arr = (unsigned*)(zn + NPIX * EDIM);   // 128 KB
    unsigned* list    = idx_arr + NPIX;                  // 128 KB (tier-2 items)
    unsigned* list2   = list + NPIX;                     // 128 KB (tier-3 pixels)
    unsigned* counter = list2 + NPIX;                    // 8 B (+pad)
    unsigned long long* packed = (unsigned long long*)(counter + 64); // 256 KB
    float2*   pv = (float2*)(packed + NPIX);             // 2 MB (8xNPIX == 16xCAP2)
    unsigned* pi = (unsigned*)(pv + KSPLIT * NPIX);      // 1 MB

    k_prep<<<NE / 4 + NPIX / 256, 256, 0, stream>>>(emb, z, e_norm, se_half,
                                                    esw, eswl, zn, counter);
    k_mfma<<<dim3(NPIX / 128, KSPLIT), 256, 0, stream>>>(zn, esw, pv, pi);
    k_merge<<<NPIX / 256, 256, 0, stream>>>(pv, pi, idx_arr, list, list2,
                                            counter, packed);
    k_rechk2<<<dim3(CAP2 / 128, KS2), 256, 0, stream>>>(zn, esw, eswl, list,
                                                        counter, pv, pi);
    k_merge2<<<CAP2 / 256, 256, 0, stream>>>(pv, pi, list, counter, list2, packed);
    k_recheck<<<1024, 256, 0, stream>>>(zn, e_norm, se_half, list2, counter, packed);
    k_finalize<<<NPIX / 64, 256, 0, stream>>>(idx_arr, packed, e_norm, out);
}

// Round 11
// 164.315 us; speedup vs baseline: 1.8225x; 1.1519x over previous
//
#include <hip/hip_runtime.h>

// VectorQuantizer: z [8,64,64,64] fp32 (BCHW), embedding [8192,64] fp32.
// Outputs (concat): z_q [8,64,64,64] fp32 (BCHW), indices [32768] as fp32.
//
// R24: candidate-shortlist refinement (kills tier-2's full rescan).
// R23 post-mortem: flag rate at MARGIN1 is ~40-45% (R17 recheck-time + R21
// CAP2-overflow both imply cnt ~15K), so tier-2's full 8192-code hi/lo scan
// was ~75-85us of hidden work. Now tier-1 tracks per-split top-3 VALUES
// (b3 = med3(v,b3,b2), one extra op) and top-2 INDICES (i2 free via the
// stuffed mantissa id). k_merge: thr = gb1 - MARGIN1;
//   - gb2 < thr            -> unflagged, write gi1 (fast path, most pixels)
//   - all splits' b3 < thr -> candidate set {i1,i2 : val >= thr} is provably
//     complete (hidden codes <= b3 < thr) -> exact fp32 rescore of <=16
//     candidates inline -> final index. No tier-2, no MARGIN2.
//   - some b3 >= thr       -> 3-way in-split near-tie (3rd index unknown) ->
//     escalate to grid-strided exact fp32 full scan (k_recheck).
// Deleted: hi/lo tier-2 MFMA kernel, eswl table, RSCL/RINV. 7 -> 5 launches.
// Tier-1 (R19-proven): fp16 1-product, NSTAGE=128, 2x16KB LDS dbuf,
// __syncthreads 2-phase loop, mantissa-id selection (med3/max).
// Staging (R12): global_load_lds 16B registerless from pre-swizzled codebook.

#define NPIX 32768
#define NE   8192
#define EDIM 64
#define HW   4096
#define NSTAGE 128          // codes per LDS stage (8 subtiles of 16)
#define KSPLIT 8
#define CPS  (NE / KSPLIT)  // 1024 codes per split
#define NSTG (CPS / NSTAGE) // 8 stages per block
#define MARGIN1 6.0e-4f
#define NSET 2              // row-sets of 16 pixels per wave (PPW=32)

typedef _Float16 f16x8 __attribute__((ext_vector_type(8)));
typedef float f32x4  __attribute__((ext_vector_type(4)));

__device__ __forceinline__ short f2h_bits(float x) {
    _Float16 h = (_Float16)x;
    short s; __builtin_memcpy(&s, &h, 2); return s;
}
// map float to unsigned with same total order
__device__ __forceinline__ unsigned int order_u32(float f) {
    unsigned int s = __float_as_uint(f);
    return (s & 0x80000000u) ? ~s : (s | 0x80000000u);
}
// async global->LDS, 16B/lane; HW writes lane i at lds_base + i*16 (wave-uniform base)
__device__ __forceinline__ void gload_lds16(const void* g, void* l) {
    __builtin_amdgcn_global_load_lds(
        (const __attribute__((address_space(1))) void*)g,
        (__attribute__((address_space(3))) void*)l, 16, 0, 0);
}

// ---------------- prep (fused): codebook (swizzled fp16) + pixels ------------
// esw layout: per 64-code group, 8 combos (sub[4] x {k0,k1}) x 1KB; within
// combo, MFMA-B fragment order: slot frag_lane=(o&3)*16+code_col holds 8
// channels (16B). A 128-code stage = two consecutive groups (16KB).
__global__ __launch_bounds__(256) void k_prep(const float* __restrict__ emb,
                                              const float* __restrict__ z,
                                              float* __restrict__ e_norm,
                                              float* __restrict__ se_half,
                                              short* __restrict__ esw,
                                              float* __restrict__ zn,
                                              unsigned* __restrict__ counter) {
    if (blockIdx.x == 0 && threadIdx.x == 0) counter[0] = 0u;
    if (blockIdx.x < NE / 4) {
        // --- codebook: 1 code per wave, lane = channel ---
        const int wave = threadIdx.x >> 6;
        const int lane = threadIdx.x & 63;
        const int n = blockIdx.x * 4 + wave;
        float v = emb[n * EDIM + lane];
        float ss = v * v;
        #pragma unroll
        for (int off = 32; off; off >>= 1) ss += __shfl_xor(ss, off, 64);
        const float inv = 1.0f / fmaxf(sqrtf(ss), 1e-12f);
        const float en = v * inv;
        e_norm[n * EDIM + lane] = en;
        // swizzled fp16 write (c = lane)
        const int grp = n >> 6, cs = n & 63;
        const int sub = cs >> 4, colb = cs & 15;
        const int o = lane >> 3, j = lane & 7;     // o: khalf=o>>2, quad=o&3
        const int slot = ((o & 3) * 16 + colb) * 8 + j;
        esw[grp * 4096 + (sub * 2 + (o >> 2)) * 512 + slot] = f2h_bits(en);
        float s2 = en * en;
        #pragma unroll
        for (int off = 32; off; off >>= 1) s2 += __shfl_xor(s2, off, 64);
        if (lane == 0) se_half[n] = 0.5f * s2;
    } else {
        // --- pixels: single-pass normalize -> zn fp32 row-major [p][c] ---
        const int p = (blockIdx.x - NE / 4) * 256 + threadIdx.x;
        const int b = p >> 12, hw = p & (HW - 1);
        const float* zp = z + b * (EDIM * HW) + hw;
        float v[EDIM];
        #pragma unroll
        for (int c = 0; c < EDIM; ++c) v[c] = zp[c * HW];
        float ss = 0.0f;
        #pragma unroll
        for (int c = 0; c < EDIM; ++c) ss = fmaf(v[c], v[c], ss);
        const float inv = 1.0f / fmaxf(sqrtf(ss), 1e-12f);
        #pragma unroll
        for (int c4 = 0; c4 < 16; ++c4) {
            float4 o;
            o.x = v[c4 * 4 + 0] * inv;
            o.y = v[c4 * 4 + 1] * inv;
            o.z = v[c4 * 4 + 2] * inv;
            o.w = v[c4 * 4 + 3] * inv;
            *(float4*)(zn + p * EDIM + c4 * 4) = o;
        }
    }
}

// ---------------- tier-1 k_mfma: split-K partial top-3 (values) -------------
// Block: 4 waves x 32 pixels = 128 pixels, one codebook eighth (blockIdx.y).
// v = dot + 2 in [1,3]; argmin dist == argmax v (unit vectors). Low 6 mantissa
// bits carry the candidate id (stage*8+sub); i1 AND i2 recovered from stuffed
// bits pre-merge. b1>=b2>=b3 invariant: b3=med3(v,b3,b2) (old b2), then
// b2=med3(v,b2,b1), then b1=max. Layouts (HW-verified):
// A[m=lane&15][k=quad*8+j], B[k=quad*8+j][n=lane&15], C/D row=(lane>>4)*4+reg,
// col=lane&15.
__global__ __launch_bounds__(256, 1) void k_mfma(const float* __restrict__ zn,
                                                 const short* __restrict__ esw,
                                                 float2* __restrict__ pv,   // [g][p] {b1,b2}
                                                 float* __restrict__ pb3,   // [g][p] b3
                                                 unsigned* __restrict__ pi, // [g][p] i1
                                                 unsigned* __restrict__ pi2)// [g][p] i2
{
    __shared__ __align__(16) short es[2][NSTAGE * EDIM];   // 2 x 16KB

    const int tid  = threadIdx.x;             // 0..255
    const int wave = tid >> 6, lane = tid & 63;
    const int quad = lane >> 4, col = lane & 15;
    const int p0   = blockIdx.x * 128 + wave * 32;  // wave's 32 pixels (2 sets)
    const int g    = blockIdx.y;                    // codebook eighth
    const int kbase = g * CPS;

    // A fragments: 2 sets of 16 pixels; fp32 zn -> fp16 (single product)
    f16x8 ah[NSET][2];
    #pragma unroll
    for (int s = 0; s < NSET; ++s) {
        const float* zr = zn + (p0 + s * 16 + col) * EDIM;
        #pragma unroll
        for (int kc = 0; kc < 2; ++kc) {
            float f[8];
            *(float4*)(f + 0) = *(const float4*)(zr + kc * 32 + quad * 8 + 0);
            *(float4*)(f + 4) = *(const float4*)(zr + kc * 32 + quad * 8 + 4);
            #pragma unroll
            for (int i = 0; i < 8; ++i) ah[s][kc][i] = (_Float16)f[i];
        }
    }

    // top-3 state in max-space; values stuffed with 6-bit id
    float b1[NSET][4], b2[NSET][4], b3[NSET][4];
    #pragma unroll
    for (int s = 0; s < NSET; ++s)
        #pragma unroll
        for (int r = 0; r < 4; ++r) { b1[s][r] = 0.0f; b2[s][r] = 0.0f; b3[s][r] = 0.0f; }

    const f32x4 cini = {2.0f, 2.0f, 2.0f, 2.0f};   // |z|=|e|=1 -> bias constant

    // this wave's staging window: src and dst are both uniform + lane*16
    const int combo0 = wave * 4;   // 16 combos x 1KB per 16KB stage
    const char* gsrc0 = (const char*)esw + (size_t)kbase * 128
                        + combo0 * 1024 + lane * 16;
    // prologue: issue stage 0 -> buf 0
    #pragma unroll
    for (int it = 0; it < 4; ++it)
        gload_lds16(gsrc0 + it * 1024, (char*)&es[0][0] + (combo0 + it) * 1024);

    for (int nb = 0; nb < NSTG; ++nb) {
        const int cur = nb & 1;
        __syncthreads();   // vmcnt drained: buf[cur] complete; buf[cur^1] reusable
        if (nb + 1 < NSTG) {
            const char* gsrc = gsrc0 + (size_t)(nb + 1) * (NSTAGE * EDIM * 2);
            #pragma unroll
            for (int it = 0; it < 4; ++it)
                gload_lds16(gsrc + it * 1024,
                            (char*)&es[cur ^ 1][0] + (combo0 + it) * 1024);
        }

        const short* esb = es[cur];
        #pragma unroll
        for (int sub = 0; sub < 8; ++sub) {       // 8 subtiles of 16 codes
            const short* base = esb + sub * 1024;
            const f16x8 bh0 = *(const f16x8*)(base + lane * 8);
            const f16x8 bh1 = *(const f16x8*)(base + 512 + lane * 8);
            const unsigned sid = (unsigned)((nb << 3) | sub);  // 6-bit id, uniform
            #pragma unroll
            for (int s = 0; s < NSET; ++s) {
                // 2-deep chain seeded with C = {2.0}
                f32x4 acc;
                acc = __builtin_amdgcn_mfma_f32_16x16x32_f16(ah[s][0], bh0, cini, 0, 0, 0);
                acc = __builtin_amdgcn_mfma_f32_16x16x32_f16(ah[s][1], bh1, acc, 0, 0, 0);
                #pragma unroll
                for (int r = 0; r < 4; ++r) {
                    // stuff candidate id into low mantissa bits (v_and_or_b32)
                    const float v = __uint_as_float(
                        (__float_as_uint(acc[r]) & 0xFFFFFFC0u) | sid);
                    // b1>=b2>=b3 invariant; b3 uses OLD b2
                    b3[s][r] = __builtin_amdgcn_fmed3f(v, b3[s][r], b2[s][r]);
                    b2[s][r] = __builtin_amdgcn_fmed3f(v, b2[s][r], b1[s][r]);
                    b1[s][r] = fmaxf(b1[s][r], v);
                }
            }
        }
    }

    // recover top-2 indices from stuffed ids (col is lane-implicit)
    int i1[NSET][4], i2[NSET][4];
    #pragma unroll
    for (int s = 0; s < NSET; ++s)
        #pragma unroll
        for (int r = 0; r < 4; ++r) {
            i1[s][r] = kbase + (int)((__float_as_uint(b1[s][r]) & 63u) << 4) + col;
            i2[s][r] = kbase + (int)((__float_as_uint(b2[s][r]) & 63u) << 4) + col;
        }

    // merge top-3 (values) + top-2 (indices) across the 16 col-lanes
    #pragma unroll
    for (int m = 1; m <= 8; m <<= 1) {
        #pragma unroll
        for (int s = 0; s < NSET; ++s)
            #pragma unroll
            for (int r = 0; r < 4; ++r) {
                const float ob1 = __shfl_xor(b1[s][r], m, 64);
                const int   oi1 = __shfl_xor(i1[s][r], m, 64);
                const float ob2 = __shfl_xor(b2[s][r], m, 64);
                const int   oi2 = __shfl_xor(i2[s][r], m, 64);
                const float ob3 = __shfl_xor(b3[s][r], m, 64);
                // tournament merge of two sorted triples
                const bool t1 = (ob1 > b1[s][r]) ||
                                (ob1 == b1[s][r] && oi1 < i1[s][r]);
                const float w2w = t1 ? ob2 : b2[s][r];   // winner-side 2nd
                const int   iw2 = t1 ? oi2 : i2[s][r];
                const float w3w = t1 ? ob3 : b3[s][r];   // winner-side 3rd
                const float l1  = t1 ? b1[s][r] : ob1;   // loser-side 1st
                const int   il1 = t1 ? i1[s][r] : oi1;
                const float l2  = t1 ? b2[s][r] : ob2;   // loser-side 2nd
                const bool t2 = w2w > l1;
                b1[s][r] = t1 ? ob1 : b1[s][r];
                i1[s][r] = t1 ? oi1 : i1[s][r];
                b2[s][r] = t2 ? w2w : l1;
                i2[s][r] = t2 ? iw2 : il1;
                b3[s][r] = t2 ? fmaxf(w3w, l1) : fmaxf(w2w, l2);
            }
    }
    if (col == 0) {
        #pragma unroll
        for (int s = 0; s < NSET; ++s)
            #pragma unroll
            for (int r = 0; r < 4; ++r) {
                const int p = p0 + s * 16 + quad * 4 + r;   // C/D row = quad*4 + r
                pv [g * NPIX + p] = make_float2(b1[s][r], b2[s][r]);
                pb3[g * NPIX + p] = b3[s][r];
                pi [g * NPIX + p] = (unsigned)i1[s][r];
                pi2[g * NPIX + p] = (unsigned)i2[s][r];
            }
    }
}

// ---------------- merge: combine splits; rescore shortlist or escalate ------
// thr = gb1 - MARGIN1. gb2 < thr -> unflagged fast path. Else if every
// split's b3 < thr, candidate set {i1,i2 : val >= thr} is complete -> exact
// fp32 rescore inline. Else escalate (3rd-in-split index unknown).
__global__ __launch_bounds__(256) void k_merge(const float2* __restrict__ pv,
                                               const float* __restrict__ pb3,
                                               const unsigned* __restrict__ pi,
                                               const unsigned* __restrict__ pi2,
                                               const float* __restrict__ zn,
                                               const float* __restrict__ e_norm,
                                               const float* __restrict__ se_half,
                                               unsigned* __restrict__ idx_arr,
                                               unsigned* __restrict__ list2,
                                               unsigned* __restrict__ counter,
                                               unsigned long long* __restrict__ packed) {
    const int p = blockIdx.x * 256 + threadIdx.x;
    float2 v[KSPLIT]; float b3[KSPLIT]; unsigned ix[KSPLIT], ix2[KSPLIT];
    #pragma unroll
    for (int gg = 0; gg < KSPLIT; ++gg) {
        v[gg]  = pv [gg * NPIX + p];
        b3[gg] = pb3[gg * NPIX + p];
        ix[gg] = pi [gg * NPIX + p];
        ix2[gg]= pi2[gg * NPIX + p];
    }
    // global noisy top-1 (ascending g + strict > == first-occurrence)
    float gb1 = v[0].x; unsigned gi1 = ix[0]; int win = 0;
    #pragma unroll
    for (int gg = 1; gg < KSPLIT; ++gg)
        if (v[gg].x > gb1) { gb1 = v[gg].x; gi1 = ix[gg]; win = gg; }
    float gb2 = -3.0e38f;
    #pragma unroll
    for (int gg = 0; gg < KSPLIT; ++gg) {
        gb2 = fmaxf(gb2, v[gg].y);
        if (gg != win) gb2 = fmaxf(gb2, v[gg].x);
    }
    const float thr = gb1 - MARGIN1;
    if (gb2 < thr) {                      // clear winner (b3 <= gb2 < thr too)
        idx_arr[p] = gi1;
        return;
    }
    bool esc = false;
    #pragma unroll
    for (int gg = 0; gg < KSPLIT; ++gg) esc |= (b3[gg] >= thr);
    if (esc) {                            // hidden 3rd-in-split possible
        packed[p] = ~0ull;
        idx_arr[p] = 0x80000000u | gi1;
        const unsigned pos = atomicAdd(&counter[0], 1u);
        if (pos < NPIX) list2[pos] = p;
        return;
    }
    // exact fp32 rescore of the complete candidate shortlist
    float zr[EDIM];
    #pragma unroll
    for (int c4 = 0; c4 < 16; ++c4)
        *(float4*)(zr + c4 * 4) = *(const float4*)(zn + (size_t)p * EDIM + c4 * 4);
    float best = 3.0e38f; int bidx = 0x7FFFFFFF;
    #pragma unroll
    for (int gg = 0; gg < KSPLIT; ++gg) {
        #pragma unroll
        for (int t = 0; t < 2; ++t) {
            const float val = t ? v[gg].y : v[gg].x;
            const int   c   = (int)(t ? ix2[gg] : ix[gg]);
            if (val >= thr) {
                const float* er = e_norm + (size_t)c * EDIM;
                float s = 0.0f;
                #pragma unroll
                for (int k = 0; k < EDIM; ++k) s = fmaf(zr[k], er[k], s);
                const float d = se_half[c] - s;
                if (d < best || (d == best && c < bidx)) { best = d; bidx = c; }
            }
        }
    }
    idx_arr[p] = (unsigned)bidx;
}

// ---------------- tier-3: exact fp32 argmin (grid-strided, parallel) ---------
// item = (pixel, 512-code chunk). Coalesced: 4 codes x 16 lanes per b128
// (contiguous 1KB from L2-resident e_norm); 4 independent shfl-reduce chains.
__global__ __launch_bounds__(256) void k_recheck(const float* __restrict__ zn,
                                                 const float* __restrict__ e_norm,
                                                 const float* __restrict__ se_half,
                                                 const unsigned* __restrict__ list2,
                                                 const unsigned* __restrict__ counter,
                                                 unsigned long long* __restrict__ packed) {
    const int lane  = threadIdx.x & 63;
    const int k     = lane >> 4;        // code-in-group 0..3
    const int m     = lane & 15;        // c4 index 0..15
    const int wglob = (blockIdx.x * 256 + threadIdx.x) >> 6;
    const int nwav  = (gridDim.x * 256) >> 6;
    int cnt = (int)counter[0]; if (cnt > NPIX) cnt = NPIX;
    const int nitems = cnt * 16;
    const float4* e4 = (const float4*)e_norm;

    for (int item = wglob; item < nitems; item += nwav) {
        const int p     = (int)list2[item >> 4];
        const int chunk = item & 15;
        const float4 zv = *(const float4*)(zn + (size_t)p * EDIM + m * 4);
        float best = 3.0e38f; int bidx = 0;
        for (int t4 = 0; t4 < 32; ++t4) {              // 16 codes per iteration
            float s[4]; int n[4];
            #pragma unroll
            for (int j = 0; j < 4; ++j) {
                n[j] = chunk * 512 + (t4 * 4 + j) * 4 + k;
                const float4 ev = e4[n[j] * 16 + m];   // lane-linear: 1KB contiguous
                s[j] = fmaf(zv.w, ev.w, fmaf(zv.z, ev.z,
                       fmaf(zv.y, ev.y, zv.x * ev.x)));
            }
            #pragma unroll
            for (int j = 0; j < 4; ++j) s[j] += __shfl_xor(s[j], 1, 64);
            #pragma unroll
            for (int j = 0; j < 4; ++j) s[j] += __shfl_xor(s[j], 2, 64);
            #pragma unroll
            for (int j = 0; j < 4; ++j) s[j] += __shfl_xor(s[j], 4, 64);
            #pragma unroll
            for (int j = 0; j < 4; ++j) s[j] += __shfl_xor(s[j], 8, 64);
            #pragma unroll
            for (int j = 0; j < 4; ++j) {              // codes ascend over (t4,j)
                const float d = se_half[n[j]] - s[j];
                if (d < best) { best = d; bidx = n[j]; }
            }
        }
        #pragma unroll
        for (int mm = 1; mm <= 32; mm <<= 1) {         // wave first-min
            const float ob = __shfl_xor(best, mm, 64);
            const int   oi = __shfl_xor(bidx, mm, 64);
            if (ob < best || (ob == best && oi < bidx)) { best = ob; bidx = oi; }
        }
        if (lane == 0) {
            const unsigned long long key =
                ((unsigned long long)order_u32(best) << 32) | (unsigned)bidx;
            atomicMin(&packed[p], key);
        }
    }
}

// ---------------- finalize: write indices + gather z_q (4 thr/pixel) ---------
__global__ __launch_bounds__(256) void k_finalize(const unsigned* __restrict__ idx_arr,
                                                  const unsigned long long* __restrict__ packed,
                                                  const float* __restrict__ e_norm,
                                                  float* __restrict__ out) {
    const int pl = threadIdx.x & 63;
    const int q  = threadIdx.x >> 6;                  // channel quarter 0..3
    const int p  = blockIdx.x * 64 + pl;
    const unsigned v = idx_arr[p];
    const int bidx = (v & 0x80000000u) ? (int)(packed[p] & 0xFFFFFFFFull)
                                       : (int)v;
    if (q == 0) out[NPIX * EDIM + p] = (float)bidx;
    const int b = p >> 12, hw = p & (HW - 1);
    float* op = out + b * (EDIM * HW) + hw;
    const float4* ep4 = (const float4*)(e_norm + (size_t)bidx * EDIM + q * 16);
    #pragma unroll
    for (int j = 0; j < 4; ++j) {
        const float4 e = ep4[j];
        const int c = q * 16 + j * 4;
        op[(c + 0) * HW] = e.x; op[(c + 1) * HW] = e.y;   // coalesced per c
        op[(c + 2) * HW] = e.z; op[(c + 3) * HW] = e.w;
    }
}

extern "C" void kernel_launch(void* const* d_in, const int* in_sizes, int n_in,
                              void* d_out, int out_size, void* d_ws, size_t ws_size,
                              hipStream_t stream) {
    const float* z   = (const float*)d_in[0];
    const float* emb = (const float*)d_in[1];
    float* out = (float*)d_out;

    // workspace layout (~16.5 MB)
    float* e_norm  = (float*)d_ws;                       // 2 MB
    float* se_half = e_norm + NE * EDIM;                 // 32 KB
    short* esw = (short*)(se_half + NE);                 // 1 MB (swizzled fp16)
    float* zn = (float*)(esw + NE * EDIM);               // 8 MB
    unsigned* idx_arr = (unsigned*)(zn + NPIX * EDIM);   // 128 KB
    unsigned* list2   = idx_arr + NPIX;                  // 128 KB (escalated)
    unsigned* counter = list2 + NPIX;                    // 4 B (+pad)
    unsigned long long* packed = (unsigned long long*)(counter + 64); // 256 KB
    float2*   pv  = (float2*)(packed + NPIX);            // 2 MB
    float*    pb3 = (float*)(pv + KSPLIT * NPIX);        // 1 MB
    unsigned* pi  = (unsigned*)(pb3 + KSPLIT * NPIX);    // 1 MB
    unsigned* pi2 = pi + KSPLIT * NPIX;                  // 1 MB

    k_prep<<<NE / 4 + NPIX / 256, 256, 0, stream>>>(emb, z, e_norm, se_half,
                                                    esw, zn, counter);
    k_mfma<<<dim3(NPIX / 128, KSPLIT), 256, 0, stream>>>(zn, esw, pv, pb3, pi, pi2);
    k_merge<<<NPIX / 256, 256, 0, stream>>>(pv, pb3, pi, pi2, zn, e_norm,
                                            se_half, idx_arr, list2, counter,
                                            packed);
    k_recheck<<<1024, 256, 0, stream>>>(zn, e_norm, se_half, list2, counter, packed);
    k_finalize<<<NPIX / 64, 256, 0, stream>>>(idx_arr, packed, e_norm, out);
}